// Round 1
// baseline (11173.427 us; speedup 1.0000x reference)
//
#include <hip/hip_runtime.h>

#define NODES 100000
#define EDGES 1600000

// ---------------- degree / norm ----------------
__global__ __launch_bounds__(256) void k_init_deg(float* __restrict__ deg, int n) {
    int i = blockIdx.x * 256 + threadIdx.x;
    if (i < n) deg[i] = 1.0f;   // self-loop weight 1
}

__global__ __launch_bounds__(256) void k_deg_scatter(float* __restrict__ deg,
                                                     const int* __restrict__ col,
                                                     const float* __restrict__ ew, int e) {
    int i = blockIdx.x * 256 + threadIdx.x;
    if (i < e) atomicAdd(&deg[col[i]], ew[i]);
}

__global__ __launch_bounds__(256) void k_dinv(float* __restrict__ deg, int n) {
    int i = blockIdx.x * 256 + threadIdx.x;
    if (i < n) deg[i] = rsqrtf(deg[i]);   // deg >= 1 always
}

// ---------------- fp32 GEMM: C[M,256] = (relu?)A[M,K] @ B[K,256] ----------------
// 64x64 tile, BK=32, 256 threads, 4x4 per thread.
template<bool RELU>
__global__ __launch_bounds__(256) void k_gemm(const float* __restrict__ A,
                                              const float* __restrict__ B,
                                              float* __restrict__ C,
                                              int M, int K) {
    __shared__ float As[32][68];   // [k][m], row stride 272B = 16B-aligned
    __shared__ float Bs[32][68];   // [k][n]
    const int tid = threadIdx.x;
    const int rowBase = blockIdx.x * 64;
    const int colBase = blockIdx.y * 64;
    const int ty = tid >> 4, tx = tid & 15;
    const int ar = tid >> 3, ac = (tid & 7) << 2;
    const int bkr = tid >> 4, bnc = (tid & 15) << 2;

    float acc[4][4] = {};

    for (int k0 = 0; k0 < K; k0 += 32) {
#pragma unroll
        for (int h = 0; h < 2; ++h) {
            int r = rowBase + ar + h * 32;
            float4 v = make_float4(0.f, 0.f, 0.f, 0.f);
            if (r < M) v = *reinterpret_cast<const float4*>(A + (size_t)r * K + k0 + ac);
            if (RELU) {
                v.x = fmaxf(v.x, 0.f); v.y = fmaxf(v.y, 0.f);
                v.z = fmaxf(v.z, 0.f); v.w = fmaxf(v.w, 0.f);
            }
            As[ac + 0][ar + h * 32] = v.x;
            As[ac + 1][ar + h * 32] = v.y;
            As[ac + 2][ar + h * 32] = v.z;
            As[ac + 3][ar + h * 32] = v.w;
        }
#pragma unroll
        for (int h = 0; h < 2; ++h) {
            int kr = bkr + h * 16;
            float4 v = *reinterpret_cast<const float4*>(B + (size_t)(k0 + kr) * 256 + colBase + bnc);
            *reinterpret_cast<float4*>(&Bs[kr][bnc]) = v;
        }
        __syncthreads();
#pragma unroll
        for (int kk = 0; kk < 32; ++kk) {
            const float4 av = *reinterpret_cast<const float4*>(&As[kk][ty << 2]);
            const float4 bv = *reinterpret_cast<const float4*>(&Bs[kk][tx << 2]);
            const float a_[4] = {av.x, av.y, av.z, av.w};
            const float b_[4] = {bv.x, bv.y, bv.z, bv.w};
#pragma unroll
            for (int i = 0; i < 4; ++i)
#pragma unroll
                for (int j = 0; j < 4; ++j)
                    acc[i][j] = fmaf(a_[i], b_[j], acc[i][j]);
        }
        __syncthreads();
    }

#pragma unroll
    for (int i = 0; i < 4; ++i) {
        int r = rowBase + (ty << 2) + i;
        if (r < M) {
            float4 v = make_float4(acc[i][0], acc[i][1], acc[i][2], acc[i][3]);
            *reinterpret_cast<float4*>(C + (size_t)r * 256 + colBase + (tx << 2)) = v;
        }
    }
}

// ---------------- P[i] = b + H[i] * dinv[i]^2  (self-loop + bias init) ----------------
__global__ __launch_bounds__(256) void k_initp(float* __restrict__ P, const float* __restrict__ H,
                                               const float* __restrict__ dinv,
                                               const float* __restrict__ bias, int n) {
    size_t idx = (size_t)blockIdx.x * 256 + threadIdx.x;   // one float4 per thread
    int i = (int)(idx >> 6);
    int j = (int)(idx & 63) << 2;
    if (i >= n) return;
    float di = dinv[i];
    float s = di * di;
    float4 h = *reinterpret_cast<const float4*>(H + (size_t)i * 256 + j);
    float4 b = *reinterpret_cast<const float4*>(bias + j);
    float4 o;
    o.x = fmaf(h.x, s, b.x); o.y = fmaf(h.y, s, b.y);
    o.z = fmaf(h.z, s, b.z); o.w = fmaf(h.w, s, b.w);
    *reinterpret_cast<float4*>(P + (size_t)i * 256 + j) = o;
}

// ---------------- edge scatter: P[col] += H[row] * (dinv[row]*ew*dinv[col]) ----------------
// one wave per edge, lane handles 4 channels (float4 gather + 4 atomics)
__global__ __launch_bounds__(256) void k_scatter(float* __restrict__ P, const float* __restrict__ H,
                                                 const float* __restrict__ dinv,
                                                 const int* __restrict__ row, const int* __restrict__ col,
                                                 const float* __restrict__ ew, int e) {
    int w = (blockIdx.x << 2) + (threadIdx.x >> 6);
    if (w >= e) return;
    int lane = threadIdx.x & 63;
    int r = row[w], c = col[w];
    float norm = dinv[r] * ew[w] * dinv[c];
    float4 h = *reinterpret_cast<const float4*>(H + (size_t)r * 256 + (lane << 2));
    float* dst = P + (size_t)c * 256 + (lane << 2);
    atomicAdd(dst + 0, h.x * norm);
    atomicAdd(dst + 1, h.y * norm);
    atomicAdd(dst + 2, h.z * norm);
    atomicAdd(dst + 3, h.w * norm);
}

// ---------------- FC: out[M,40] = relu(X[M,256]) @ W[256,40] + b ----------------
__global__ __launch_bounds__(256) void k_fc(float* __restrict__ out, const float* __restrict__ X,
                                            const float* __restrict__ W, const float* __restrict__ bias,
                                            int M) {
    __shared__ float Ws[256 * 40];   // 40 KB
    __shared__ float Xs[32][68];
    const int tid = threadIdx.x;
#pragma unroll
    for (int t = 0; t < 10; ++t) {   // 2560 float4s, 10 per thread
        int idx = (t * 256 + tid) * 4;
        *reinterpret_cast<float4*>(&Ws[idx]) = *reinterpret_cast<const float4*>(W + idx);
    }
    const int rowBase = blockIdx.x * 64;
    const int r  = tid >> 2;          // 0..63
    const int cg = (tid & 3) * 10;    // col group: 10 cols
    const int ar = tid >> 3, ac = (tid & 7) << 2;
    float acc[10] = {};

    for (int k0 = 0; k0 < 256; k0 += 32) {
#pragma unroll
        for (int h = 0; h < 2; ++h) {
            int rr = rowBase + ar + h * 32;
            float4 v = make_float4(0.f, 0.f, 0.f, 0.f);
            if (rr < M) v = *reinterpret_cast<const float4*>(X + (size_t)rr * 256 + k0 + ac);
            v.x = fmaxf(v.x, 0.f); v.y = fmaxf(v.y, 0.f);
            v.z = fmaxf(v.z, 0.f); v.w = fmaxf(v.w, 0.f);
            Xs[ac + 0][ar + h * 32] = v.x;
            Xs[ac + 1][ar + h * 32] = v.y;
            Xs[ac + 2][ar + h * 32] = v.z;
            Xs[ac + 3][ar + h * 32] = v.w;
        }
        __syncthreads();   // Xs ready (and Ws on first iter)
#pragma unroll
        for (int kk = 0; kk < 32; ++kk) {
            float xv = Xs[kk][r];
#pragma unroll
            for (int j = 0; j < 10; ++j)
                acc[j] = fmaf(xv, Ws[(k0 + kk) * 40 + cg + j], acc[j]);
        }
        __syncthreads();   // done reading Xs before next overwrite
    }

    int orow = rowBase + r;
    if (orow < M) {
#pragma unroll
        for (int j = 0; j < 10; ++j)
            out[(size_t)orow * 40 + cg + j] = acc[j] + bias[cg + j];
    }
}

extern "C" void kernel_launch(void* const* d_in, const int* in_sizes, int n_in,
                              void* d_out, int out_size, void* d_ws, size_t ws_size,
                              hipStream_t stream) {
    const float* x   = (const float*)d_in[0];
    const int*   ei  = (const int*)d_in[1];     // integer inputs arrive as int32
    const float* ea  = (const float*)d_in[2];
    const float* W1  = (const float*)d_in[3];
    const float* b1  = (const float*)d_in[4];
    const float* W2  = (const float*)d_in[5];
    const float* b2  = (const float*)d_in[6];
    const float* fcW = (const float*)d_in[7];
    const float* fcb = (const float*)d_in[8];
    float* out = (float*)d_out;

    const int n = NODES, e = EDGES;
    const int* row = ei;
    const int* col = ei + e;

    char* ws = (char*)d_ws;
    float* dinv = (float*)ws;                                  // 400,000 B
    float* A    = (float*)(ws + (1u << 20));                   // 102,400,000 B  (H buffer)
    float* B    = (float*)(ws + (1u << 20) + 102400000u);      // 102,400,000 B  (P buffer)

    // norm precompute (shared by both layers)
    k_init_deg<<<(n + 255) / 256, 256, 0, stream>>>(dinv, n);
    k_deg_scatter<<<e / 256, 256, 0, stream>>>(dinv, col, ea, e);
    k_dinv<<<(n + 255) / 256, 256, 0, stream>>>(dinv, n);

    dim3 gemm_grid((n + 63) / 64, 4);

    // layer 1: H1 = x @ W1 ; P1 = b1 + dinv^2*H1 ; scatter ; (relu fused into next gemm)
    k_gemm<false><<<gemm_grid, 256, 0, stream>>>(x, W1, A, n, 128);
    k_initp<<<(n * 64 + 255) / 256, 256, 0, stream>>>(B, A, dinv, b1, n);
    k_scatter<<<e / 4, 256, 0, stream>>>(B, A, dinv, row, col, ea, e);

    // layer 2: H2 = relu(P1) @ W2 ; P2 = b2 + dinv^2*H2 ; scatter
    k_gemm<true><<<gemm_grid, 256, 0, stream>>>(B, W2, A, n, 256);
    k_initp<<<(n * 64 + 255) / 256, 256, 0, stream>>>(B, A, dinv, b2, n);
    k_scatter<<<e / 4, 256, 0, stream>>>(B, A, dinv, row, col, ea, e);

    // classifier: out = relu(P2) @ fcW + fcb
    k_fc<<<(n + 63) / 64, 256, 0, stream>>>(out, B, fcW, fcb, n);
}

// Round 2
// 1266.794 us; speedup vs baseline: 8.8202x; 8.8202x over previous
//
#include <hip/hip_runtime.h>

#define NODES 100000
#define EDGES 1600000

// ---------------- init: deg=1 (self loop), cnt=0 ----------------
__global__ __launch_bounds__(256) void k_init(float* __restrict__ deg, int* __restrict__ cnt, int n) {
    int i = blockIdx.x * 256 + threadIdx.x;
    if (i < n) { deg[i] = 1.0f; cnt[i] = 0; }
}

// ---------------- per-edge: degree accumulate + histogram ----------------
__global__ __launch_bounds__(256) void k_deg_hist(float* __restrict__ deg, int* __restrict__ cnt,
                                                  const int* __restrict__ col,
                                                  const float* __restrict__ ew, int e) {
    int i = blockIdx.x * 256 + threadIdx.x;
    if (i < e) {
        int c = col[i];
        atomicAdd(&deg[c], ew[i]);
        atomicAdd(&cnt[c], 1);
    }
}

__global__ __launch_bounds__(256) void k_dinv(float* __restrict__ deg, int n) {
    int i = blockIdx.x * 256 + threadIdx.x;
    if (i < n) deg[i] = rsqrtf(deg[i]);   // deg >= 1 always (self loop)
}

// ---------------- single-block exclusive scan: cnt[0..n) -> rowptr[0..n] ----------------
__global__ __launch_bounds__(1024) void k_scan(const int* __restrict__ cnt, int* __restrict__ rowptr, int n) {
    __shared__ int wsum[16];
    __shared__ int blocktot;
    const int tid = threadIdx.x, lane = tid & 63, wid = tid >> 6;
    int running = 0;
    for (int base = 0; base < n; base += 1024) {
        int i = base + tid;
        int v = (i < n) ? cnt[i] : 0;
        int incl = v;
#pragma unroll
        for (int off = 1; off < 64; off <<= 1) {
            int t = __shfl_up(incl, off, 64);
            if (lane >= off) incl += t;
        }
        if (lane == 63) wsum[wid] = incl;
        __syncthreads();
        if (wid == 0) {
            int s = (lane < 16) ? wsum[lane] : 0;
#pragma unroll
            for (int off = 1; off < 16; off <<= 1) {
                int t = __shfl_up(s, off, 64);
                if (lane >= off) s += t;
            }
            if (lane < 16) wsum[lane] = s;
            if (lane == 15) blocktot = s;
        }
        __syncthreads();
        int woff = (wid == 0) ? 0 : wsum[wid - 1];
        if (i < n) rowptr[i] = running + woff + incl - v;   // exclusive
        running += blocktot;
        __syncthreads();   // protect wsum/blocktot before next iteration overwrites
    }
    if (tid == 0) rowptr[n] = running;   // == e
}

__global__ __launch_bounds__(256) void k_copy(const int* __restrict__ src, int* __restrict__ dst, int n) {
    int i = blockIdx.x * 256 + threadIdx.x;
    if (i < n) dst[i] = src[i];
}

// ---------------- counting-sort build: meta[pos] = (srcRow, normWeight) ----------------
__global__ __launch_bounds__(256) void k_build(int* __restrict__ cursor, int2* __restrict__ meta,
                                               const int* __restrict__ row, const int* __restrict__ col,
                                               const float* __restrict__ ew,
                                               const float* __restrict__ dinv, int e) {
    int i = blockIdx.x * 256 + threadIdx.x;
    if (i >= e) return;
    int r = row[i], c = col[i];
    float w = dinv[r] * ew[i] * dinv[c];
    int pos = atomicAdd(&cursor[c], 1);
    meta[pos] = make_int2(r, __float_as_int(w));
}

// ---------------- gather-reduce: P[c] = b + dinv[c]^2*H[c] + sum_e w_e * H[row_e] ----------------
// one wave per dest node; lane handles 4 channels
__global__ __launch_bounds__(256) void k_gather(float* __restrict__ P, const float* __restrict__ H,
                                                const float* __restrict__ dinv,
                                                const int* __restrict__ rowptr,
                                                const int2* __restrict__ meta,
                                                const float* __restrict__ bias, int n) {
    int node = (blockIdx.x << 2) + (threadIdx.x >> 6);
    if (node >= n) return;
    const int lane = threadIdx.x & 63;
    const int j = lane << 2;
    float di = dinv[node];
    float s = di * di;
    float4 b = *reinterpret_cast<const float4*>(bias + j);
    float4 hs = *reinterpret_cast<const float4*>(H + (size_t)node * 256 + j);
    float4 acc;
    acc.x = fmaf(hs.x, s, b.x); acc.y = fmaf(hs.y, s, b.y);
    acc.z = fmaf(hs.z, s, b.z); acc.w = fmaf(hs.w, s, b.w);
    float4 acc2 = make_float4(0.f, 0.f, 0.f, 0.f);

    int p = rowptr[node];
    const int end = rowptr[node + 1];
    for (; p + 1 < end; p += 2) {
        int2 m0 = meta[p];
        int2 m1 = meta[p + 1];
        float4 h0 = *reinterpret_cast<const float4*>(H + (size_t)m0.x * 256 + j);
        float4 h1 = *reinterpret_cast<const float4*>(H + (size_t)m1.x * 256 + j);
        float w0 = __int_as_float(m0.y);
        float w1 = __int_as_float(m1.y);
        acc.x  = fmaf(h0.x, w0, acc.x);  acc.y  = fmaf(h0.y, w0, acc.y);
        acc.z  = fmaf(h0.z, w0, acc.z);  acc.w  = fmaf(h0.w, w0, acc.w);
        acc2.x = fmaf(h1.x, w1, acc2.x); acc2.y = fmaf(h1.y, w1, acc2.y);
        acc2.z = fmaf(h1.z, w1, acc2.z); acc2.w = fmaf(h1.w, w1, acc2.w);
    }
    if (p < end) {
        int2 m0 = meta[p];
        float4 h0 = *reinterpret_cast<const float4*>(H + (size_t)m0.x * 256 + j);
        float w0 = __int_as_float(m0.y);
        acc.x = fmaf(h0.x, w0, acc.x); acc.y = fmaf(h0.y, w0, acc.y);
        acc.z = fmaf(h0.z, w0, acc.z); acc.w = fmaf(h0.w, w0, acc.w);
    }
    acc.x += acc2.x; acc.y += acc2.y; acc.z += acc2.z; acc.w += acc2.w;
    *reinterpret_cast<float4*>(P + (size_t)node * 256 + j) = acc;
}

// ---------------- fp32 GEMM: C[M,256] = (relu?)A[M,K] @ B[K,256] ----------------
template<bool RELU>
__global__ __launch_bounds__(256) void k_gemm(const float* __restrict__ A,
                                              const float* __restrict__ B,
                                              float* __restrict__ C,
                                              int M, int K) {
    __shared__ float As[32][68];
    __shared__ float Bs[32][68];
    const int tid = threadIdx.x;
    const int rowBase = blockIdx.x * 64;
    const int colBase = blockIdx.y * 64;
    const int ty = tid >> 4, tx = tid & 15;
    const int ar = tid >> 3, ac = (tid & 7) << 2;
    const int bkr = tid >> 4, bnc = (tid & 15) << 2;

    float acc[4][4] = {};

    for (int k0 = 0; k0 < K; k0 += 32) {
#pragma unroll
        for (int h = 0; h < 2; ++h) {
            int r = rowBase + ar + h * 32;
            float4 v = make_float4(0.f, 0.f, 0.f, 0.f);
            if (r < M) v = *reinterpret_cast<const float4*>(A + (size_t)r * K + k0 + ac);
            if (RELU) {
                v.x = fmaxf(v.x, 0.f); v.y = fmaxf(v.y, 0.f);
                v.z = fmaxf(v.z, 0.f); v.w = fmaxf(v.w, 0.f);
            }
            As[ac + 0][ar + h * 32] = v.x;
            As[ac + 1][ar + h * 32] = v.y;
            As[ac + 2][ar + h * 32] = v.z;
            As[ac + 3][ar + h * 32] = v.w;
        }
#pragma unroll
        for (int h = 0; h < 2; ++h) {
            int kr = bkr + h * 16;
            float4 v = *reinterpret_cast<const float4*>(B + (size_t)(k0 + kr) * 256 + colBase + bnc);
            *reinterpret_cast<float4*>(&Bs[kr][bnc]) = v;
        }
        __syncthreads();
#pragma unroll
        for (int kk = 0; kk < 32; ++kk) {
            const float4 av = *reinterpret_cast<const float4*>(&As[kk][ty << 2]);
            const float4 bv = *reinterpret_cast<const float4*>(&Bs[kk][tx << 2]);
            const float a_[4] = {av.x, av.y, av.z, av.w};
            const float b_[4] = {bv.x, bv.y, bv.z, bv.w};
#pragma unroll
            for (int i = 0; i < 4; ++i)
#pragma unroll
                for (int j = 0; j < 4; ++j)
                    acc[i][j] = fmaf(a_[i], b_[j], acc[i][j]);
        }
        __syncthreads();
    }

#pragma unroll
    for (int i = 0; i < 4; ++i) {
        int r = rowBase + (ty << 2) + i;
        if (r < M) {
            float4 v = make_float4(acc[i][0], acc[i][1], acc[i][2], acc[i][3]);
            *reinterpret_cast<float4*>(C + (size_t)r * 256 + colBase + (tx << 2)) = v;
        }
    }
}

// ---------------- FC: out[M,40] = relu(X[M,256]) @ W[256,40] + b ----------------
__global__ __launch_bounds__(256) void k_fc(float* __restrict__ out, const float* __restrict__ X,
                                            const float* __restrict__ W, const float* __restrict__ bias,
                                            int M) {
    __shared__ float Ws[256 * 40];
    __shared__ float Xs[32][68];
    const int tid = threadIdx.x;
#pragma unroll
    for (int t = 0; t < 10; ++t) {
        int idx = (t * 256 + tid) * 4;
        *reinterpret_cast<float4*>(&Ws[idx]) = *reinterpret_cast<const float4*>(W + idx);
    }
    const int rowBase = blockIdx.x * 64;
    const int r  = tid >> 2;
    const int cg = (tid & 3) * 10;
    const int ar = tid >> 3, ac = (tid & 7) << 2;
    float acc[10] = {};

    for (int k0 = 0; k0 < 256; k0 += 32) {
#pragma unroll
        for (int h = 0; h < 2; ++h) {
            int rr = rowBase + ar + h * 32;
            float4 v = make_float4(0.f, 0.f, 0.f, 0.f);
            if (rr < M) v = *reinterpret_cast<const float4*>(X + (size_t)rr * 256 + k0 + ac);
            v.x = fmaxf(v.x, 0.f); v.y = fmaxf(v.y, 0.f);
            v.z = fmaxf(v.z, 0.f); v.w = fmaxf(v.w, 0.f);
            Xs[ac + 0][ar + h * 32] = v.x;
            Xs[ac + 1][ar + h * 32] = v.y;
            Xs[ac + 2][ar + h * 32] = v.z;
            Xs[ac + 3][ar + h * 32] = v.w;
        }
        __syncthreads();
#pragma unroll
        for (int kk = 0; kk < 32; ++kk) {
            float xv = Xs[kk][r];
#pragma unroll
            for (int j = 0; j < 10; ++j)
                acc[j] = fmaf(xv, Ws[(k0 + kk) * 40 + cg + j], acc[j]);
        }
        __syncthreads();
    }

    int orow = rowBase + r;
    if (orow < M) {
#pragma unroll
        for (int j = 0; j < 10; ++j)
            out[(size_t)orow * 40 + cg + j] = acc[j] + bias[cg + j];
    }
}

extern "C" void kernel_launch(void* const* d_in, const int* in_sizes, int n_in,
                              void* d_out, int out_size, void* d_ws, size_t ws_size,
                              hipStream_t stream) {
    const float* x   = (const float*)d_in[0];
    const int*   ei  = (const int*)d_in[1];
    const float* ea  = (const float*)d_in[2];
    const float* W1  = (const float*)d_in[3];
    const float* b1  = (const float*)d_in[4];
    const float* W2  = (const float*)d_in[5];
    const float* b2  = (const float*)d_in[6];
    const float* fcW = (const float*)d_in[7];
    const float* fcb = (const float*)d_in[8];
    float* out = (float*)d_out;

    const int n = NODES, e = EDGES;
    const int* row = ei;
    const int* col = ei + e;

    // workspace layout (16B aligned)
    char* ws = (char*)d_ws;
    float* A      = (float*)ws;                              // 102,400,000 B (H)
    float* B      = (float*)(ws + 102400000u);               // 102,400,000 B (P)
    float* dinv   = (float*)(ws + 204800000u);               // 400,000 B
    int*   cnt    = (int*)  (ws + 205200000u);               // 400,000 B (also cursor)
    int*   rowptr = (int*)  (ws + 205600000u);               // 400,016 B (n+1 ints)
    int2*  meta   = (int2*) (ws + 206000016u);               // 12,800,000 B
                                                             // total ~218.8 MB

    const int nb = (n + 255) / 256;
    const int eb = e / 256;   // 6250 exact

    // ---- norm + CSR build (shared by both layers) ----
    k_init<<<nb, 256, 0, stream>>>(dinv, cnt, n);
    k_deg_hist<<<eb, 256, 0, stream>>>(dinv, cnt, col, ea, e);
    k_dinv<<<nb, 256, 0, stream>>>(dinv, n);
    k_scan<<<1, 1024, 0, stream>>>(cnt, rowptr, n);
    k_copy<<<nb, 256, 0, stream>>>(rowptr, cnt, n);          // cnt becomes cursor
    k_build<<<eb, 256, 0, stream>>>(cnt, meta, row, col, ea, dinv, e);

    dim3 gemm_grid((n + 63) / 64, 4);

    // layer 1: H1 = x @ W1 ; P1 = gather(H1)  (relu fused into next gemm's load)
    k_gemm<false><<<gemm_grid, 256, 0, stream>>>(x, W1, A, n, 128);
    k_gather<<<(n + 3) / 4, 256, 0, stream>>>(B, A, dinv, rowptr, meta, b1, n);

    // layer 2: H2 = relu(P1) @ W2 ; P2 = gather(H2)
    k_gemm<true><<<gemm_grid, 256, 0, stream>>>(B, W2, A, n, 256);
    k_gather<<<(n + 3) / 4, 256, 0, stream>>>(B, A, dinv, rowptr, meta, b2, n);

    // classifier: out = relu(P2) @ fcW + fcb
    k_fc<<<(n + 63) / 64, 256, 0, stream>>>(out, B, fcW, fcb, n);
}

// Round 3
// 1122.345 us; speedup vs baseline: 9.9554x; 1.1287x over previous
//
#include <hip/hip_runtime.h>

#define NODES 100000
#define EDGES 1600000

typedef __attribute__((ext_vector_type(8))) short short8;
typedef __attribute__((ext_vector_type(4))) float floatx4;

__device__ inline unsigned short bf16_rne(float x) {
    unsigned u = __float_as_uint(x);
    u += 0x7FFF + ((u >> 16) & 1);
    return (unsigned short)(u >> 16);
}

// ---------------- init: deg=1 (self loop), cnt=0 ----------------
__global__ __launch_bounds__(256) void k_init(float* __restrict__ deg, int* __restrict__ cnt, int n) {
    int i = blockIdx.x * 256 + threadIdx.x;
    if (i < n) { deg[i] = 1.0f; cnt[i] = 0; }
}

__global__ __launch_bounds__(256) void k_deg_hist(float* __restrict__ deg, int* __restrict__ cnt,
                                                  const int* __restrict__ col,
                                                  const float* __restrict__ ew, int e) {
    int i = blockIdx.x * 256 + threadIdx.x;
    if (i < e) {
        int c = col[i];
        atomicAdd(&deg[c], ew[i]);
        atomicAdd(&cnt[c], 1);
    }
}

__global__ __launch_bounds__(256) void k_dinv(float* __restrict__ deg, int n) {
    int i = blockIdx.x * 256 + threadIdx.x;
    if (i < n) deg[i] = rsqrtf(deg[i]);
}

// ---------------- single-block exclusive scan ----------------
__global__ __launch_bounds__(1024) void k_scan(const int* __restrict__ cnt, int* __restrict__ rowptr, int n) {
    __shared__ int wsum[16];
    __shared__ int blocktot;
    const int tid = threadIdx.x, lane = tid & 63, wid = tid >> 6;
    int running = 0;
    for (int base = 0; base < n; base += 1024) {
        int i = base + tid;
        int v = (i < n) ? cnt[i] : 0;
        int incl = v;
#pragma unroll
        for (int off = 1; off < 64; off <<= 1) {
            int t = __shfl_up(incl, off, 64);
            if (lane >= off) incl += t;
        }
        if (lane == 63) wsum[wid] = incl;
        __syncthreads();
        if (wid == 0) {
            int s = (lane < 16) ? wsum[lane] : 0;
#pragma unroll
            for (int off = 1; off < 16; off <<= 1) {
                int t = __shfl_up(s, off, 64);
                if (lane >= off) s += t;
            }
            if (lane < 16) wsum[lane] = s;
            if (lane == 15) blocktot = s;
        }
        __syncthreads();
        int woff = (wid == 0) ? 0 : wsum[wid - 1];
        if (i < n) rowptr[i] = running + woff + incl - v;
        running += blocktot;
        __syncthreads();
    }
    if (tid == 0) rowptr[n] = running;
}

__global__ __launch_bounds__(256) void k_copy(const int* __restrict__ src, int* __restrict__ dst, int n) {
    int i = blockIdx.x * 256 + threadIdx.x;
    if (i < n) dst[i] = src[i];
}

__global__ __launch_bounds__(256) void k_build(int* __restrict__ cursor, int2* __restrict__ meta,
                                               const int* __restrict__ row, const int* __restrict__ col,
                                               const float* __restrict__ ew,
                                               const float* __restrict__ dinv, int e) {
    int i = blockIdx.x * 256 + threadIdx.x;
    if (i >= e) return;
    int r = row[i], c = col[i];
    float w = dinv[r] * ew[i] * dinv[c];
    int pos = atomicAdd(&cursor[c], 1);
    meta[pos] = make_int2(r, __float_as_int(w));
}

// ---------------- gather-reduce ----------------
__global__ __launch_bounds__(256) void k_gather(float* __restrict__ P, const float* __restrict__ H,
                                                const float* __restrict__ dinv,
                                                const int* __restrict__ rowptr,
                                                const int2* __restrict__ meta,
                                                const float* __restrict__ bias, int n) {
    int node = (blockIdx.x << 2) + (threadIdx.x >> 6);
    if (node >= n) return;
    const int lane = threadIdx.x & 63;
    const int j = lane << 2;
    float di = dinv[node];
    float s = di * di;
    float4 b = *reinterpret_cast<const float4*>(bias + j);
    float4 hs = *reinterpret_cast<const float4*>(H + (size_t)node * 256 + j);
    float4 acc;
    acc.x = fmaf(hs.x, s, b.x); acc.y = fmaf(hs.y, s, b.y);
    acc.z = fmaf(hs.z, s, b.z); acc.w = fmaf(hs.w, s, b.w);
    float4 acc2 = make_float4(0.f, 0.f, 0.f, 0.f);

    int p = rowptr[node];
    const int end = rowptr[node + 1];
    for (; p + 1 < end; p += 2) {
        int2 m0 = meta[p];
        int2 m1 = meta[p + 1];
        float4 h0 = *reinterpret_cast<const float4*>(H + (size_t)m0.x * 256 + j);
        float4 h1 = *reinterpret_cast<const float4*>(H + (size_t)m1.x * 256 + j);
        float w0 = __int_as_float(m0.y);
        float w1 = __int_as_float(m1.y);
        acc.x  = fmaf(h0.x, w0, acc.x);  acc.y  = fmaf(h0.y, w0, acc.y);
        acc.z  = fmaf(h0.z, w0, acc.z);  acc.w  = fmaf(h0.w, w0, acc.w);
        acc2.x = fmaf(h1.x, w1, acc2.x); acc2.y = fmaf(h1.y, w1, acc2.y);
        acc2.z = fmaf(h1.z, w1, acc2.z); acc2.w = fmaf(h1.w, w1, acc2.w);
    }
    if (p < end) {
        int2 m0 = meta[p];
        float4 h0 = *reinterpret_cast<const float4*>(H + (size_t)m0.x * 256 + j);
        float w0 = __int_as_float(m0.y);
        acc.x = fmaf(h0.x, w0, acc.x); acc.y = fmaf(h0.y, w0, acc.y);
        acc.z = fmaf(h0.z, w0, acc.z); acc.w = fmaf(h0.w, w0, acc.w);
    }
    acc.x += acc2.x; acc.y += acc2.y; acc.z += acc2.z; acc.w += acc2.w;
    *reinterpret_cast<float4*>(P + (size_t)node * 256 + j) = acc;
}

// ---------------- W split+transpose: W[K,256] -> Bt_hi/Bt_lo [256,K] bf16 ----------------
__global__ __launch_bounds__(256) void k_splitB(const float* __restrict__ W,
                                                unsigned short* __restrict__ Bth,
                                                unsigned short* __restrict__ Btl, int K) {
    int idx = blockIdx.x * 256 + threadIdx.x;
    if (idx >= K * 256) return;
    int k = idx >> 8, nn = idx & 255;
    float v = W[idx];
    unsigned short h = bf16_rne(v);
    float hf = __uint_as_float((unsigned)h << 16);
    unsigned short l = bf16_rne(v - hf);
    Bth[nn * K + k] = h;
    Btl[nn * K + k] = l;
}

// ---------------- split-bf16 MFMA GEMM: C[M,256] = (relu?)A[M,K] @ W[K,256] ----------------
// C ~= Ah@Bh + Ah@Bl + Al@Bh ; 128x128 tile, BK=32, 4 waves, 16x16x32 bf16 MFMA
template<bool RELU>
__global__ __launch_bounds__(256) void k_gemm_mfma(const float* __restrict__ A,
                                                   const unsigned short* __restrict__ Bth,
                                                   const unsigned short* __restrict__ Btl,
                                                   float* __restrict__ C, int M, int K) {
    __shared__ unsigned short Ah[128 * 32];
    __shared__ unsigned short Al[128 * 32];
    __shared__ unsigned short Bh[128 * 32];
    __shared__ unsigned short Bl[128 * 32];
    const int tid = threadIdx.x;
    const int lane = tid & 63, wid = tid >> 6;
    const int quad = lane >> 4, l16 = lane & 15;
    const int rowBase = blockIdx.x * 128;
    const int colBase = blockIdx.y * 128;
    const int wm = (wid & 1) * 64, wn = (wid >> 1) * 64;

    floatx4 acc[4][4] = {};

    for (int k0 = 0; k0 < K; k0 += 32) {
        // stage A tile (128 rows x 32 k), split to bf16 hi/lo: 4 float4 per thread
#pragma unroll
        for (int i = 0; i < 4; ++i) {
            int idx = tid + i * 256;          // 0..1023
            int r = idx >> 3;                 // 0..127
            int kq = (idx & 7) << 2;          // 0..28
            float4 v = make_float4(0.f, 0.f, 0.f, 0.f);
            int gr = rowBase + r;
            if (gr < M) v = *reinterpret_cast<const float4*>(A + (size_t)gr * K + k0 + kq);
            if (RELU) {
                v.x = fmaxf(v.x, 0.f); v.y = fmaxf(v.y, 0.f);
                v.z = fmaxf(v.z, 0.f); v.w = fmaxf(v.w, 0.f);
            }
            ushort4 hh, ll;
            hh.x = bf16_rne(v.x); ll.x = bf16_rne(v.x - __uint_as_float((unsigned)hh.x << 16));
            hh.y = bf16_rne(v.y); ll.y = bf16_rne(v.y - __uint_as_float((unsigned)hh.y << 16));
            hh.z = bf16_rne(v.z); ll.z = bf16_rne(v.z - __uint_as_float((unsigned)hh.z << 16));
            hh.w = bf16_rne(v.w); ll.w = bf16_rne(v.w - __uint_as_float((unsigned)hh.w << 16));
            *reinterpret_cast<ushort4*>(&Ah[r * 32 + kq]) = hh;
            *reinterpret_cast<ushort4*>(&Al[r * 32 + kq]) = ll;
        }
        // stage B tiles (128 n x 32 k bf16, already [N,K]): 2 x 16B per thread per matrix
#pragma unroll
        for (int i = 0; i < 2; ++i) {
            int idx = tid + i * 256;          // 0..511
            int r = idx >> 2;                 // 0..127
            int kq = (idx & 3) << 3;          // 0,8,16,24
            size_t goff = (size_t)(colBase + r) * K + k0 + kq;
            float4 hv = *reinterpret_cast<const float4*>(Bth + goff);
            float4 lv = *reinterpret_cast<const float4*>(Btl + goff);
            *reinterpret_cast<float4*>(&Bh[r * 32 + kq]) = hv;
            *reinterpret_cast<float4*>(&Bl[r * 32 + kq]) = lv;
        }
        __syncthreads();

        short8 afh[4], afl[4], bfh[4], bfl[4];
#pragma unroll
        for (int mi = 0; mi < 4; ++mi) {
            int off = (wm + mi * 16 + l16) * 32 + quad * 8;
            afh[mi] = *reinterpret_cast<const short8*>(&Ah[off]);
            afl[mi] = *reinterpret_cast<const short8*>(&Al[off]);
        }
#pragma unroll
        for (int ni = 0; ni < 4; ++ni) {
            int off = (wn + ni * 16 + l16) * 32 + quad * 8;
            bfh[ni] = *reinterpret_cast<const short8*>(&Bh[off]);
            bfl[ni] = *reinterpret_cast<const short8*>(&Bl[off]);
        }
#pragma unroll
        for (int mi = 0; mi < 4; ++mi)
#pragma unroll
            for (int ni = 0; ni < 4; ++ni) {
                acc[mi][ni] = __builtin_amdgcn_mfma_f32_16x16x32_bf16(afh[mi], bfh[ni], acc[mi][ni], 0, 0, 0);
                acc[mi][ni] = __builtin_amdgcn_mfma_f32_16x16x32_bf16(afh[mi], bfl[ni], acc[mi][ni], 0, 0, 0);
                acc[mi][ni] = __builtin_amdgcn_mfma_f32_16x16x32_bf16(afl[mi], bfh[ni], acc[mi][ni], 0, 0, 0);
            }
        __syncthreads();
    }

    // store: C/D layout col=l16, row=quad*4+reg
#pragma unroll
    for (int mi = 0; mi < 4; ++mi) {
#pragma unroll
        for (int r = 0; r < 4; ++r) {
            int grow = rowBase + wm + mi * 16 + quad * 4 + r;
            if (grow < M) {
#pragma unroll
                for (int ni = 0; ni < 4; ++ni)
                    C[(size_t)grow * 256 + colBase + wn + ni * 16 + l16] = acc[mi][ni][r];
            }
        }
    }
}

// ---------------- FC: out[M,40] = relu(X[M,256]) @ W[256,40] + b ----------------
__global__ __launch_bounds__(256) void k_fc(float* __restrict__ out, const float* __restrict__ X,
                                            const float* __restrict__ W, const float* __restrict__ bias,
                                            int M) {
    __shared__ float Ws[256 * 40];
    __shared__ float Xs[32][68];
    const int tid = threadIdx.x;
#pragma unroll
    for (int t = 0; t < 10; ++t) {
        int idx = (t * 256 + tid) * 4;
        *reinterpret_cast<float4*>(&Ws[idx]) = *reinterpret_cast<const float4*>(W + idx);
    }
    const int rowBase = blockIdx.x * 64;
    const int r  = tid >> 2;
    const int cg = (tid & 3) * 10;
    const int ar = tid >> 3, ac = (tid & 7) << 2;
    float acc[10] = {};

    for (int k0 = 0; k0 < 256; k0 += 32) {
#pragma unroll
        for (int h = 0; h < 2; ++h) {
            int rr = rowBase + ar + h * 32;
            float4 v = make_float4(0.f, 0.f, 0.f, 0.f);
            if (rr < M) v = *reinterpret_cast<const float4*>(X + (size_t)rr * 256 + k0 + ac);
            v.x = fmaxf(v.x, 0.f); v.y = fmaxf(v.y, 0.f);
            v.z = fmaxf(v.z, 0.f); v.w = fmaxf(v.w, 0.f);
            Xs[ac + 0][ar + h * 32] = v.x;
            Xs[ac + 1][ar + h * 32] = v.y;
            Xs[ac + 2][ar + h * 32] = v.z;
            Xs[ac + 3][ar + h * 32] = v.w;
        }
        __syncthreads();
#pragma unroll
        for (int kk = 0; kk < 32; ++kk) {
            float xv = Xs[kk][r];
#pragma unroll
            for (int j = 0; j < 10; ++j)
                acc[j] = fmaf(xv, Ws[(k0 + kk) * 40 + cg + j], acc[j]);
        }
        __syncthreads();
    }

    int orow = rowBase + r;
    if (orow < M) {
#pragma unroll
        for (int j = 0; j < 10; ++j)
            out[(size_t)orow * 40 + cg + j] = acc[j] + bias[cg + j];
    }
}

extern "C" void kernel_launch(void* const* d_in, const int* in_sizes, int n_in,
                              void* d_out, int out_size, void* d_ws, size_t ws_size,
                              hipStream_t stream) {
    const float* x   = (const float*)d_in[0];
    const int*   ei  = (const int*)d_in[1];
    const float* ea  = (const float*)d_in[2];
    const float* W1  = (const float*)d_in[3];
    const float* b1  = (const float*)d_in[4];
    const float* W2  = (const float*)d_in[5];
    const float* b2  = (const float*)d_in[6];
    const float* fcW = (const float*)d_in[7];
    const float* fcb = (const float*)d_in[8];
    float* out = (float*)d_out;

    const int n = NODES, e = EDGES;
    const int* row = ei;
    const int* col = ei + e;

    char* ws = (char*)d_ws;
    float* A      = (float*)ws;                               // 102,400,000 B (H)
    float* B      = (float*)(ws + 102400000u);                // 102,400,000 B (P)
    float* dinv   = (float*)(ws + 204800000u);                // 400,000 B
    int*   cnt    = (int*)  (ws + 205200000u);                // 400,000 B
    int*   rowptr = (int*)  (ws + 205600000u);                // 400,016 B
    int2*  meta   = (int2*) (ws + 206000016u);                // 12,800,000 B -> ends 218,800,016
    unsigned short* W1th = (unsigned short*)(ws + 218800016u); // 65,536 B
    unsigned short* W1tl = (unsigned short*)(ws + 218865552u); // 65,536 B
    unsigned short* W2th = (unsigned short*)(ws + 218931088u); // 131,072 B
    unsigned short* W2tl = (unsigned short*)(ws + 219062160u); // 131,072 B -> ends 219,193,232

    const int nb = (n + 255) / 256;
    const int eb = e / 256;

    // ---- norm + CSR build + weight splits ----
    k_init<<<nb, 256, 0, stream>>>(dinv, cnt, n);
    k_deg_hist<<<eb, 256, 0, stream>>>(dinv, cnt, col, ea, e);
    k_dinv<<<nb, 256, 0, stream>>>(dinv, n);
    k_scan<<<1, 1024, 0, stream>>>(cnt, rowptr, n);
    k_copy<<<nb, 256, 0, stream>>>(rowptr, cnt, n);
    k_build<<<eb, 256, 0, stream>>>(cnt, meta, row, col, ea, dinv, e);
    k_splitB<<<128, 256, 0, stream>>>(W1, W1th, W1tl, 128);
    k_splitB<<<256, 256, 0, stream>>>(W2, W2th, W2tl, 256);

    dim3 gg((n + 127) / 128, 2);

    // layer 1: H1 = x @ W1 ; P1 = gather(H1)
    k_gemm_mfma<false><<<gg, 256, 0, stream>>>(x, W1th, W1tl, A, n, 128);
    k_gather<<<(n + 3) / 4, 256, 0, stream>>>(B, A, dinv, rowptr, meta, b1, n);

    // layer 2: H2 = relu(P1) @ W2 ; P2 = gather(H2)
    k_gemm_mfma<true><<<gg, 256, 0, stream>>>(B, W2th, W2tl, A, n, 256);
    k_gather<<<(n + 3) / 4, 256, 0, stream>>>(B, A, dinv, rowptr, meta, b2, n);

    // classifier
    k_fc<<<(n + 63) / 64, 256, 0, stream>>>(out, B, fcW, fcb, n);
}

// Round 4
// 1049.973 us; speedup vs baseline: 10.6416x; 1.0689x over previous
//
#include <hip/hip_runtime.h>

#define NODES 100000
#define EDGES 1600000

typedef __attribute__((ext_vector_type(8))) short short8;
typedef __attribute__((ext_vector_type(4))) float floatx4;

__device__ inline unsigned short bf16_rne(float x) {
    unsigned u = __float_as_uint(x);
    u += 0x7FFF + ((u >> 16) & 1);
    return (unsigned short)(u >> 16);
}

__device__ inline void load_lds16(void* lds, const void* g) {
    __builtin_amdgcn_global_load_lds((const __attribute__((address_space(1))) void*)g,
                                     (__attribute__((address_space(3))) void*)lds, 16, 0, 0);
}

// ---------------- init / degree / norm ----------------
__global__ __launch_bounds__(256) void k_init(float* __restrict__ deg, int* __restrict__ cnt, int n) {
    int i = blockIdx.x * 256 + threadIdx.x;
    if (i < n) { deg[i] = 1.0f; cnt[i] = 0; }
}

__global__ __launch_bounds__(256) void k_deg_hist(float* __restrict__ deg, int* __restrict__ cnt,
                                                  const int* __restrict__ col,
                                                  const float* __restrict__ ew, int e) {
    int i = blockIdx.x * 256 + threadIdx.x;
    if (i < e) {
        int c = col[i];
        atomicAdd(&deg[c], ew[i]);
        atomicAdd(&cnt[c], 1);
    }
}

__global__ __launch_bounds__(256) void k_dinv(float* __restrict__ deg, int n) {
    int i = blockIdx.x * 256 + threadIdx.x;
    if (i < n) deg[i] = rsqrtf(deg[i]);
}

// ---------------- 3-phase parallel exclusive scan ----------------
__global__ __launch_bounds__(256) void k_scan1(const int* __restrict__ cnt, int* __restrict__ rowptr,
                                               int* __restrict__ partials, int n) {
    __shared__ int wtot[4];
    const int tid = threadIdx.x, lane = tid & 63, wid = tid >> 6;
    int i = blockIdx.x * 256 + tid;
    int v = (i < n) ? cnt[i] : 0;
    int incl = v;
#pragma unroll
    for (int off = 1; off < 64; off <<= 1) {
        int t = __shfl_up(incl, off, 64);
        if (lane >= off) incl += t;
    }
    if (lane == 63) wtot[wid] = incl;
    __syncthreads();
    int woff = 0;
    for (int k = 0; k < wid; ++k) woff += wtot[k];
    if (i < n) rowptr[i] = woff + incl - v;
    if (tid == 255) partials[blockIdx.x] = woff + incl;
}

__global__ __launch_bounds__(512) void k_scan2(int* __restrict__ partials, int nb) {
    __shared__ int wtot[8];
    const int tid = threadIdx.x, lane = tid & 63, wid = tid >> 6;
    int v = (tid < nb) ? partials[tid] : 0;
    int incl = v;
#pragma unroll
    for (int off = 1; off < 64; off <<= 1) {
        int t = __shfl_up(incl, off, 64);
        if (lane >= off) incl += t;
    }
    if (lane == 63) wtot[wid] = incl;
    __syncthreads();
    int woff = 0;
    for (int k = 0; k < wid; ++k) woff += wtot[k];
    if (tid < nb) partials[tid] = woff + incl - v;   // exclusive
}

__global__ __launch_bounds__(256) void k_scan3(int* __restrict__ rowptr, const int* __restrict__ partials, int n) {
    int i = blockIdx.x * 256 + threadIdx.x;
    if (i < n) rowptr[i] += partials[blockIdx.x];
    if (blockIdx.x == 0 && threadIdx.x == 0) rowptr[n] = EDGES;
}

__global__ __launch_bounds__(256) void k_copy(const int* __restrict__ src, int* __restrict__ dst, int n) {
    int i = blockIdx.x * 256 + threadIdx.x;
    if (i < n) dst[i] = src[i];
}

__global__ __launch_bounds__(256) void k_build(int* __restrict__ cursor, int2* __restrict__ meta,
                                               const int* __restrict__ row, const int* __restrict__ col,
                                               const float* __restrict__ ew,
                                               const float* __restrict__ dinv, int e) {
    int i = blockIdx.x * 256 + threadIdx.x;
    if (i >= e) return;
    int r = row[i], c = col[i];
    float w = dinv[r] * ew[i] * dinv[c];
    int pos = atomicAdd(&cursor[c], 1);
    meta[pos] = make_int2(r, __float_as_int(w));
}

// ---------------- gather-reduce; SPLIT: write relu+bf16 hi/lo, else fp32 ----------------
template<bool SPLIT>
__global__ __launch_bounds__(256) void k_gather(float* __restrict__ P,
                                                unsigned short* __restrict__ Ph,
                                                unsigned short* __restrict__ Pl,
                                                const float* __restrict__ H,
                                                const float* __restrict__ dinv,
                                                const int* __restrict__ rowptr,
                                                const int2* __restrict__ meta,
                                                const float* __restrict__ bias, int n) {
    int node = (blockIdx.x << 2) + (threadIdx.x >> 6);
    if (node >= n) return;
    const int lane = threadIdx.x & 63;
    const int j = lane << 2;
    float di = dinv[node];
    float s = di * di;
    float4 b = *reinterpret_cast<const float4*>(bias + j);
    float4 hs = *reinterpret_cast<const float4*>(H + (size_t)node * 256 + j);
    float4 acc;
    acc.x = fmaf(hs.x, s, b.x); acc.y = fmaf(hs.y, s, b.y);
    acc.z = fmaf(hs.z, s, b.z); acc.w = fmaf(hs.w, s, b.w);
    float4 acc2 = make_float4(0.f, 0.f, 0.f, 0.f);

    int p = rowptr[node];
    const int end = rowptr[node + 1];
    for (; p + 1 < end; p += 2) {
        int2 m0 = meta[p];
        int2 m1 = meta[p + 1];
        float4 h0 = *reinterpret_cast<const float4*>(H + (size_t)m0.x * 256 + j);
        float4 h1 = *reinterpret_cast<const float4*>(H + (size_t)m1.x * 256 + j);
        float w0 = __int_as_float(m0.y);
        float w1 = __int_as_float(m1.y);
        acc.x  = fmaf(h0.x, w0, acc.x);  acc.y  = fmaf(h0.y, w0, acc.y);
        acc.z  = fmaf(h0.z, w0, acc.z);  acc.w  = fmaf(h0.w, w0, acc.w);
        acc2.x = fmaf(h1.x, w1, acc2.x); acc2.y = fmaf(h1.y, w1, acc2.y);
        acc2.z = fmaf(h1.z, w1, acc2.z); acc2.w = fmaf(h1.w, w1, acc2.w);
    }
    if (p < end) {
        int2 m0 = meta[p];
        float4 h0 = *reinterpret_cast<const float4*>(H + (size_t)m0.x * 256 + j);
        float w0 = __int_as_float(m0.y);
        acc.x = fmaf(h0.x, w0, acc.x); acc.y = fmaf(h0.y, w0, acc.y);
        acc.z = fmaf(h0.z, w0, acc.z); acc.w = fmaf(h0.w, w0, acc.w);
    }
    acc.x += acc2.x; acc.y += acc2.y; acc.z += acc2.z; acc.w += acc2.w;

    if (SPLIT) {
        // relu then bf16 hi/lo split (feeds next GEMM's A operand)
        float4 r;
        r.x = fmaxf(acc.x, 0.f); r.y = fmaxf(acc.y, 0.f);
        r.z = fmaxf(acc.z, 0.f); r.w = fmaxf(acc.w, 0.f);
        ushort4 hh, ll;
        hh.x = bf16_rne(r.x); ll.x = bf16_rne(r.x - __uint_as_float((unsigned)hh.x << 16));
        hh.y = bf16_rne(r.y); ll.y = bf16_rne(r.y - __uint_as_float((unsigned)hh.y << 16));
        hh.z = bf16_rne(r.z); ll.z = bf16_rne(r.z - __uint_as_float((unsigned)hh.z << 16));
        hh.w = bf16_rne(r.w); ll.w = bf16_rne(r.w - __uint_as_float((unsigned)hh.w << 16));
        *reinterpret_cast<ushort4*>(Ph + (size_t)node * 256 + j) = hh;
        *reinterpret_cast<ushort4*>(Pl + (size_t)node * 256 + j) = ll;
    } else {
        *reinterpret_cast<float4*>(P + (size_t)node * 256 + j) = acc;
    }
}

// ---------------- pre-split x -> bf16 hi/lo ----------------
__global__ __launch_bounds__(256) void k_splitA(const float* __restrict__ X,
                                                unsigned short* __restrict__ Xh,
                                                unsigned short* __restrict__ Xl, int total4) {
    int i = blockIdx.x * 256 + threadIdx.x;
    if (i >= total4) return;
    float4 v = reinterpret_cast<const float4*>(X)[i];
    ushort4 hh, ll;
    hh.x = bf16_rne(v.x); ll.x = bf16_rne(v.x - __uint_as_float((unsigned)hh.x << 16));
    hh.y = bf16_rne(v.y); ll.y = bf16_rne(v.y - __uint_as_float((unsigned)hh.y << 16));
    hh.z = bf16_rne(v.z); ll.z = bf16_rne(v.z - __uint_as_float((unsigned)hh.z << 16));
    hh.w = bf16_rne(v.w); ll.w = bf16_rne(v.w - __uint_as_float((unsigned)hh.w << 16));
    reinterpret_cast<ushort4*>(Xh)[i] = hh;
    reinterpret_cast<ushort4*>(Xl)[i] = ll;
}

// ---------------- W split+transpose: W[K,256] -> [256,K] bf16 hi/lo ----------------
__global__ __launch_bounds__(256) void k_splitB(const float* __restrict__ W,
                                                unsigned short* __restrict__ Bth,
                                                unsigned short* __restrict__ Btl, int K) {
    int idx = blockIdx.x * 256 + threadIdx.x;
    if (idx >= K * 256) return;
    int k = idx >> 8, nn = idx & 255;
    float v = W[idx];
    unsigned short h = bf16_rne(v);
    float hf = __uint_as_float((unsigned)h << 16);
    unsigned short l = bf16_rne(v - hf);
    Bth[nn * K + k] = h;
    Btl[nn * K + k] = l;
}

// ---------------- split-bf16 MFMA GEMM, pre-split operands ----------------
// C[M,256] ~= Ah@Bh^T + Ah@Bl^T + Al@Bh^T ; A [M,K] bf16 row-major, B [256,K] bf16
// 128x128 tile, BK=32, 4 waves. global_load_lds staging, chunk-swizzled LDS.
__global__ __launch_bounds__(256) void k_gemm_bf16(const unsigned short* __restrict__ Ahg,
                                                   const unsigned short* __restrict__ Alg,
                                                   const unsigned short* __restrict__ Bth,
                                                   const unsigned short* __restrict__ Btl,
                                                   float* __restrict__ C, int M, int K) {
    // chunk layout: idx = (row>>4)*64 + quad*16 + (row&15), each chunk = 16B (8 bf16, k=quad*8..)
    __shared__ __attribute__((aligned(16))) char ldsAh[8192];
    __shared__ __attribute__((aligned(16))) char ldsAl[8192];
    __shared__ __attribute__((aligned(16))) char ldsBh[8192];
    __shared__ __attribute__((aligned(16))) char ldsBl[8192];
    const int tid = threadIdx.x;
    const int lane = tid & 63, wid = tid >> 6;
    const int quad = lane >> 4, l16 = lane & 15;
    const int rowBase = blockIdx.x * 128;
    const int colBase = blockIdx.y * 128;
    const int wm = (wid & 1) * 64, wn = (wid >> 1) * 64;

    floatx4 acc[4][4] = {};

    // staging decode: chunk c -> row = (c>>6)*16 + (c&15), k-quad = (c>>4)&3
    const int c0 = wid * 64 + lane;
    const int c1 = c0 + 256;
    const int r0 = ((c0 >> 6) << 4) + (c0 & 15), q0 = (c0 >> 4) & 3;
    const int r1 = ((c1 >> 6) << 4) + (c1 & 15), q1 = (c1 >> 4) & 3;
    const size_t aoff0 = (size_t)(rowBase + r0) * K + q0 * 8;
    const size_t aoff1 = (size_t)(rowBase + r1) * K + q1 * 8;
    const size_t boff0 = (size_t)(colBase + r0) * K + q0 * 8;
    const size_t boff1 = (size_t)(colBase + r1) * K + q1 * 8;
    const int lo0 = (wid * 64) * 16;
    const int lo1 = (256 + wid * 64) * 16;

    for (int k0 = 0; k0 < K; k0 += 32) {
        load_lds16(ldsAh + lo0, Ahg + aoff0 + k0);
        load_lds16(ldsAh + lo1, Ahg + aoff1 + k0);
        load_lds16(ldsAl + lo0, Alg + aoff0 + k0);
        load_lds16(ldsAl + lo1, Alg + aoff1 + k0);
        load_lds16(ldsBh + lo0, Bth + boff0 + k0);
        load_lds16(ldsBh + lo1, Bth + boff1 + k0);
        load_lds16(ldsBl + lo0, Btl + boff0 + k0);
        load_lds16(ldsBl + lo1, Btl + boff1 + k0);
        __syncthreads();

        const short8* vAh = (const short8*)ldsAh;
        const short8* vAl = (const short8*)ldsAl;
        const short8* vBh = (const short8*)ldsBh;
        const short8* vBl = (const short8*)ldsBl;
        short8 afh[4], afl[4], bfh[4], bfl[4];
#pragma unroll
        for (int mi = 0; mi < 4; ++mi) {
            int idx = ((wm >> 4) + mi) * 64 + quad * 16 + l16;
            afh[mi] = vAh[idx];
            afl[mi] = vAl[idx];
        }
#pragma unroll
        for (int ni = 0; ni < 4; ++ni) {
            int idx = ((wn >> 4) + ni) * 64 + quad * 16 + l16;
            bfh[ni] = vBh[idx];
            bfl[ni] = vBl[idx];
        }
#pragma unroll
        for (int mi = 0; mi < 4; ++mi)
#pragma unroll
            for (int ni = 0; ni < 4; ++ni) {
                acc[mi][ni] = __builtin_amdgcn_mfma_f32_16x16x32_bf16(afh[mi], bfh[ni], acc[mi][ni], 0, 0, 0);
                acc[mi][ni] = __builtin_amdgcn_mfma_f32_16x16x32_bf16(afh[mi], bfl[ni], acc[mi][ni], 0, 0, 0);
                acc[mi][ni] = __builtin_amdgcn_mfma_f32_16x16x32_bf16(afl[mi], bfh[ni], acc[mi][ni], 0, 0, 0);
            }
        __syncthreads();
    }

    // C/D layout: col=l16, row=quad*4+reg
#pragma unroll
    for (int mi = 0; mi < 4; ++mi) {
#pragma unroll
        for (int r = 0; r < 4; ++r) {
            int grow = rowBase + wm + mi * 16 + quad * 4 + r;
            if (grow < M) {
#pragma unroll
                for (int ni = 0; ni < 4; ++ni)
                    C[(size_t)grow * 256 + colBase + wn + ni * 16 + l16] = acc[mi][ni][r];
            }
        }
    }
}

// ---------------- FC: out[M,40] = relu(X[M,256]) @ W[256,40] + b ----------------
__global__ __launch_bounds__(256) void k_fc(float* __restrict__ out, const float* __restrict__ X,
                                            const float* __restrict__ W, const float* __restrict__ bias,
                                            int M) {
    __shared__ float Ws[256 * 40];
    __shared__ float Xs[32][68];
    const int tid = threadIdx.x;
#pragma unroll
    for (int t = 0; t < 10; ++t) {
        int idx = (t * 256 + tid) * 4;
        *reinterpret_cast<float4*>(&Ws[idx]) = *reinterpret_cast<const float4*>(W + idx);
    }
    const int rowBase = blockIdx.x * 64;
    const int r  = tid >> 2;
    const int cg = (tid & 3) * 10;
    const int ar = tid >> 3, ac = (tid & 7) << 2;
    float acc[10] = {};

    for (int k0 = 0; k0 < 256; k0 += 32) {
#pragma unroll
        for (int h = 0; h < 2; ++h) {
            int rr = rowBase + ar + h * 32;
            float4 v = make_float4(0.f, 0.f, 0.f, 0.f);
            if (rr < M) v = *reinterpret_cast<const float4*>(X + (size_t)rr * 256 + k0 + ac);
            v.x = fmaxf(v.x, 0.f); v.y = fmaxf(v.y, 0.f);
            v.z = fmaxf(v.z, 0.f); v.w = fmaxf(v.w, 0.f);
            Xs[ac + 0][ar + h * 32] = v.x;
            Xs[ac + 1][ar + h * 32] = v.y;
            Xs[ac + 2][ar + h * 32] = v.z;
            Xs[ac + 3][ar + h * 32] = v.w;
        }
        __syncthreads();
#pragma unroll
        for (int kk = 0; kk < 32; ++kk) {
            float xv = Xs[kk][r];
#pragma unroll
            for (int j = 0; j < 10; ++j)
                acc[j] = fmaf(xv, Ws[(k0 + kk) * 40 + cg + j], acc[j]);
        }
        __syncthreads();
    }

    int orow = rowBase + r;
    if (orow < M) {
#pragma unroll
        for (int j = 0; j < 10; ++j)
            out[(size_t)orow * 40 + cg + j] = acc[j] + bias[cg + j];
    }
}

extern "C" void kernel_launch(void* const* d_in, const int* in_sizes, int n_in,
                              void* d_out, int out_size, void* d_ws, size_t ws_size,
                              hipStream_t stream) {
    const float* x   = (const float*)d_in[0];
    const int*   ei  = (const int*)d_in[1];
    const float* ea  = (const float*)d_in[2];
    const float* W1  = (const float*)d_in[3];
    const float* b1  = (const float*)d_in[4];
    const float* W2  = (const float*)d_in[5];
    const float* b2  = (const float*)d_in[6];
    const float* fcW = (const float*)d_in[7];
    const float* fcb = (const float*)d_in[8];
    float* out = (float*)d_out;

    const int n = NODES, e = EDGES;
    const int* row = ei;
    const int* col = ei + e;

    char* ws = (char*)d_ws;
    float* A      = (float*)ws;                                // 102,400,000 B (H fp32)
    char*  Breg   = ws + 102400000u;                           // 102,400,000 B (time-shared)
    float* dinv   = (float*)(ws + 204800000u);                 // 400,000 B
    int*   cnt    = (int*)  (ws + 205200000u);                 // 400,000 B
    int*   rowptr = (int*)  (ws + 205600000u);                 // 400,016 B
    int2*  meta   = (int2*) (ws + 206000016u);                 // 12,800,000 B
    unsigned short* W1th = (unsigned short*)(ws + 218800016u); // 65,536 B
    unsigned short* W1tl = (unsigned short*)(ws + 218865552u); // 65,536 B
    unsigned short* W2th = (unsigned short*)(ws + 218931088u); // 131,072 B
    unsigned short* W2tl = (unsigned short*)(ws + 219062160u); // 131,072 B -> ends 219,193,232

    // B-region overlays (time-shared):
    unsigned short* Xh = (unsigned short*)Breg;                 // 25.6 MB  (phase 1: GEMM1 input)
    unsigned short* Xl = (unsigned short*)(Breg + 25600000u);   // 25.6 MB
    unsigned short* Ph = (unsigned short*)Breg;                 // 51.2 MB  (phase 2: gather1 out)
    unsigned short* Pl = (unsigned short*)(Breg + 51200000u);   // 51.2 MB
    float* P2 = (float*)Breg;                                   // 102.4 MB (phase 3: gather2 out)
    int* partials = (int*)ws;                                   // scan temp, lives in A region

    const int nb = (n + 255) / 256;   // 391
    const int eb = e / 256;           // 6250

    // ---- norm + CSR build ----
    k_init<<<nb, 256, 0, stream>>>(dinv, cnt, n);
    k_deg_hist<<<eb, 256, 0, stream>>>(dinv, cnt, col, ea, e);
    k_dinv<<<nb, 256, 0, stream>>>(dinv, n);
    k_scan1<<<nb, 256, 0, stream>>>(cnt, rowptr, partials, n);
    k_scan2<<<1, 512, 0, stream>>>(partials, nb);
    k_scan3<<<nb, 256, 0, stream>>>(rowptr, partials, n);
    k_copy<<<nb, 256, 0, stream>>>(rowptr, cnt, n);
    k_build<<<eb, 256, 0, stream>>>(cnt, meta, row, col, ea, dinv, e);

    // ---- weight / input splits ----
    k_splitB<<<128, 256, 0, stream>>>(W1, W1th, W1tl, 128);
    k_splitB<<<256, 256, 0, stream>>>(W2, W2th, W2tl, 256);
    k_splitA<<<(n * 32 + 255) / 256, 256, 0, stream>>>(x, Xh, Xl, n * 32);  // 100000*128/4

    dim3 gg((n + 127) / 128, 2);

    // layer 1: H1 = x @ W1 (A) ; gather -> relu+split bf16 (Ph/Pl)
    k_gemm_bf16<<<gg, 256, 0, stream>>>(Xh, Xl, W1th, W1tl, A, n, 128);
    k_gather<true><<<(n + 3) / 4, 256, 0, stream>>>(nullptr, Ph, Pl, A, dinv, rowptr, meta, b1, n);

    // layer 2: H2 = relu(P1) @ W2 (A) ; gather -> fp32 P2
    k_gemm_bf16<<<gg, 256, 0, stream>>>(Ph, Pl, W2th, W2tl, A, n, 256);
    k_gather<false><<<(n + 3) / 4, 256, 0, stream>>>(P2, nullptr, nullptr, A, dinv, rowptr, meta, b2, n);

    // classifier
    k_fc<<<(n + 63) / 64, 256, 0, stream>>>(out, P2, fcW, fcb, n);
}

// Round 5
// 928.756 us; speedup vs baseline: 12.0305x; 1.1305x over previous
//
#include <hip/hip_runtime.h>

#define NODES 100000
#define EDGES 1600000

typedef __attribute__((ext_vector_type(8))) short short8;
typedef __attribute__((ext_vector_type(4))) float floatx4;

__device__ inline unsigned short bf16_rne(float x) {
    unsigned u = __float_as_uint(x);
    u += 0x7FFF + ((u >> 16) & 1);
    return (unsigned short)(u >> 16);
}

__device__ inline void load_lds16(void* lds, const void* g) {
    __builtin_amdgcn_global_load_lds((const __attribute__((address_space(1))) void*)g,
                                     (__attribute__((address_space(3))) void*)lds, 16, 0, 0);
}

// ---------------- init / degree ----------------
__global__ __launch_bounds__(256) void k_init(float* __restrict__ deg, int* __restrict__ cnt, int n) {
    int i = blockIdx.x * 256 + threadIdx.x;
    if (i < n) { deg[i] = 1.0f; cnt[i] = 0; }
}

__global__ __launch_bounds__(256) void k_deg_hist(float* __restrict__ deg, int* __restrict__ cnt,
                                                  const int* __restrict__ col,
                                                  const float* __restrict__ ew, int e) {
    int i = blockIdx.x * 256 + threadIdx.x;
    if (i < e) {
        int c = col[i];
        atomicAdd(&deg[c], ew[i]);
        atomicAdd(&cnt[c], 1);
    }
}

// ---------------- scan phase 1 (+ fused dinv) ----------------
__global__ __launch_bounds__(256) void k_scan1(const int* __restrict__ cnt, int* __restrict__ rowptr,
                                               int* __restrict__ partials, float* __restrict__ deg, int n) {
    __shared__ int wtot[4];
    const int tid = threadIdx.x, lane = tid & 63, wid = tid >> 6;
    int i = blockIdx.x * 256 + tid;
    if (i < n) deg[i] = rsqrtf(deg[i]);   // fused dinv
    int v = (i < n) ? cnt[i] : 0;
    int incl = v;
#pragma unroll
    for (int off = 1; off < 64; off <<= 1) {
        int t = __shfl_up(incl, off, 64);
        if (lane >= off) incl += t;
    }
    if (lane == 63) wtot[wid] = incl;
    __syncthreads();
    int woff = 0;
    for (int k = 0; k < wid; ++k) woff += wtot[k];
    if (i < n) rowptr[i] = woff + incl - v;
    if (tid == 255) partials[blockIdx.x] = woff + incl;
}

__global__ __launch_bounds__(512) void k_scan2(int* __restrict__ partials, int nb) {
    __shared__ int wtot[8];
    const int tid = threadIdx.x, lane = tid & 63, wid = tid >> 6;
    int v = (tid < nb) ? partials[tid] : 0;
    int incl = v;
#pragma unroll
    for (int off = 1; off < 64; off <<= 1) {
        int t = __shfl_up(incl, off, 64);
        if (lane >= off) incl += t;
    }
    if (lane == 63) wtot[wid] = incl;
    __syncthreads();
    int woff = 0;
    for (int k = 0; k < wid; ++k) woff += wtot[k];
    if (tid < nb) partials[tid] = woff + incl - v;   // exclusive
}

// scan phase 3 (+ fused cursor copy)
__global__ __launch_bounds__(256) void k_scan3(int* __restrict__ rowptr, int* __restrict__ cursor,
                                               const int* __restrict__ partials, int n) {
    int i = blockIdx.x * 256 + threadIdx.x;
    if (i < n) {
        int v = rowptr[i] + partials[blockIdx.x];
        rowptr[i] = v;
        cursor[i] = v;
    }
    if (blockIdx.x == 0 && threadIdx.x == 0) rowptr[n] = EDGES;
}

__global__ __launch_bounds__(256) void k_build(int* __restrict__ cursor, int2* __restrict__ meta,
                                               const int* __restrict__ row, const int* __restrict__ col,
                                               const float* __restrict__ ew,
                                               const float* __restrict__ dinv, int e) {
    int i = blockIdx.x * 256 + threadIdx.x;
    if (i >= e) return;
    int r = row[i], c = col[i];
    float w = dinv[r] * ew[i] * dinv[c];
    int pos = atomicAdd(&cursor[c], 1);
    meta[pos] = make_int2(r, __float_as_int(w));
}

// ---------------- gather on raw x (128 ch): Xagg = agg(x), epilogue bf16 split ----------------
__global__ __launch_bounds__(256) void k_gather_x(unsigned short* __restrict__ Xh,
                                                  unsigned short* __restrict__ Xl,
                                                  const float* __restrict__ x,
                                                  const float* __restrict__ dinv,
                                                  const int* __restrict__ rowptr,
                                                  const int2* __restrict__ meta, int n) {
    int node = (blockIdx.x << 2) + (threadIdx.x >> 6);
    if (node >= n) return;
    const int lane = threadIdx.x & 63;
    const int j = lane << 1;   // channel pair
    float di = dinv[node];
    float s = di * di;
    float2 xs = *reinterpret_cast<const float2*>(x + (size_t)node * 128 + j);
    float2 a0 = make_float2(xs.x * s, xs.y * s);
    float2 a1 = make_float2(0.f, 0.f);

    int p = rowptr[node];
    const int end = rowptr[node + 1];
    for (; p + 3 < end; p += 4) {
        int2 m0 = meta[p],     m1 = meta[p + 1];
        int2 m2 = meta[p + 2], m3 = meta[p + 3];
        float2 h0 = *reinterpret_cast<const float2*>(x + (size_t)m0.x * 128 + j);
        float2 h1 = *reinterpret_cast<const float2*>(x + (size_t)m1.x * 128 + j);
        float2 h2 = *reinterpret_cast<const float2*>(x + (size_t)m2.x * 128 + j);
        float2 h3 = *reinterpret_cast<const float2*>(x + (size_t)m3.x * 128 + j);
        float w0 = __int_as_float(m0.y), w1 = __int_as_float(m1.y);
        float w2 = __int_as_float(m2.y), w3 = __int_as_float(m3.y);
        a0.x = fmaf(h0.x, w0, a0.x); a0.y = fmaf(h0.y, w0, a0.y);
        a1.x = fmaf(h1.x, w1, a1.x); a1.y = fmaf(h1.y, w1, a1.y);
        a0.x = fmaf(h2.x, w2, a0.x); a0.y = fmaf(h2.y, w2, a0.y);
        a1.x = fmaf(h3.x, w3, a1.x); a1.y = fmaf(h3.y, w3, a1.y);
    }
    for (; p < end; ++p) {
        int2 m0 = meta[p];
        float2 h0 = *reinterpret_cast<const float2*>(x + (size_t)m0.x * 128 + j);
        float w0 = __int_as_float(m0.y);
        a0.x = fmaf(h0.x, w0, a0.x); a0.y = fmaf(h0.y, w0, a0.y);
    }
    a0.x += a1.x; a0.y += a1.y;

    ushort2 hh, ll;
    hh.x = bf16_rne(a0.x); ll.x = bf16_rne(a0.x - __uint_as_float((unsigned)hh.x << 16));
    hh.y = bf16_rne(a0.y); ll.y = bf16_rne(a0.y - __uint_as_float((unsigned)hh.y << 16));
    *reinterpret_cast<ushort2*>(Xh + (size_t)node * 128 + j) = hh;
    *reinterpret_cast<ushort2*>(Xl + (size_t)node * 128 + j) = ll;
}

// ---------------- gather-reduce (256 ch fp32, + bias) ----------------
__global__ __launch_bounds__(256) void k_gather(float* __restrict__ P,
                                                const float* __restrict__ H,
                                                const float* __restrict__ dinv,
                                                const int* __restrict__ rowptr,
                                                const int2* __restrict__ meta,
                                                const float* __restrict__ bias, int n) {
    int node = (blockIdx.x << 2) + (threadIdx.x >> 6);
    if (node >= n) return;
    const int lane = threadIdx.x & 63;
    const int j = lane << 2;
    float di = dinv[node];
    float s = di * di;
    float4 b = *reinterpret_cast<const float4*>(bias + j);
    float4 hs = *reinterpret_cast<const float4*>(H + (size_t)node * 256 + j);
    float4 acc;
    acc.x = fmaf(hs.x, s, b.x); acc.y = fmaf(hs.y, s, b.y);
    acc.z = fmaf(hs.z, s, b.z); acc.w = fmaf(hs.w, s, b.w);
    float4 acc2 = make_float4(0.f, 0.f, 0.f, 0.f);

    int p = rowptr[node];
    const int end = rowptr[node + 1];
    for (; p + 3 < end; p += 4) {
        int2 m0 = meta[p],     m1 = meta[p + 1];
        int2 m2 = meta[p + 2], m3 = meta[p + 3];
        float4 h0 = *reinterpret_cast<const float4*>(H + (size_t)m0.x * 256 + j);
        float4 h1 = *reinterpret_cast<const float4*>(H + (size_t)m1.x * 256 + j);
        float4 h2 = *reinterpret_cast<const float4*>(H + (size_t)m2.x * 256 + j);
        float4 h3 = *reinterpret_cast<const float4*>(H + (size_t)m3.x * 256 + j);
        float w0 = __int_as_float(m0.y), w1 = __int_as_float(m1.y);
        float w2 = __int_as_float(m2.y), w3 = __int_as_float(m3.y);
        acc.x  = fmaf(h0.x, w0, acc.x);  acc.y  = fmaf(h0.y, w0, acc.y);
        acc.z  = fmaf(h0.z, w0, acc.z);  acc.w  = fmaf(h0.w, w0, acc.w);
        acc2.x = fmaf(h1.x, w1, acc2.x); acc2.y = fmaf(h1.y, w1, acc2.y);
        acc2.z = fmaf(h1.z, w1, acc2.z); acc2.w = fmaf(h1.w, w1, acc2.w);
        acc.x  = fmaf(h2.x, w2, acc.x);  acc.y  = fmaf(h2.y, w2, acc.y);
        acc.z  = fmaf(h2.z, w2, acc.z);  acc.w  = fmaf(h2.w, w2, acc.w);
        acc2.x = fmaf(h3.x, w3, acc2.x); acc2.y = fmaf(h3.y, w3, acc2.y);
        acc2.z = fmaf(h3.z, w3, acc2.z); acc2.w = fmaf(h3.w, w3, acc2.w);
    }
    for (; p < end; ++p) {
        int2 m0 = meta[p];
        float4 h0 = *reinterpret_cast<const float4*>(H + (size_t)m0.x * 256 + j);
        float w0 = __int_as_float(m0.y);
        acc.x = fmaf(h0.x, w0, acc.x); acc.y = fmaf(h0.y, w0, acc.y);
        acc.z = fmaf(h0.z, w0, acc.z); acc.w = fmaf(h0.w, w0, acc.w);
    }
    acc.x += acc2.x; acc.y += acc2.y; acc.z += acc2.z; acc.w += acc2.w;
    *reinterpret_cast<float4*>(P + (size_t)node * 256 + j) = acc;
}

// ---------------- W split+transpose: W[K,256] -> [256,K] bf16 hi/lo ----------------
__global__ __launch_bounds__(256) void k_splitB(const float* __restrict__ W,
                                                unsigned short* __restrict__ Bth,
                                                unsigned short* __restrict__ Btl, int K) {
    int idx = blockIdx.x * 256 + threadIdx.x;
    if (idx >= K * 256) return;
    int k = idx >> 8, nn = idx & 255;
    float v = W[idx];
    unsigned short h = bf16_rne(v);
    float hf = __uint_as_float((unsigned)h << 16);
    unsigned short l = bf16_rne(v - hf);
    Bth[nn * K + k] = h;
    Btl[nn * K + k] = l;
}

// ---------------- split-bf16 MFMA GEMM ----------------
// C ~= Ah@Bh^T + Ah@Bl^T + Al@Bh^T ; A [M,K] bf16, B [256,K] bf16.
// SPLIT epilogue: v = acc + bias, relu, bf16 hi/lo -> Ph/Pl. Else fp32 -> C.
template<bool SPLIT>
__global__ __launch_bounds__(256) void k_gemm_bf16(const unsigned short* __restrict__ Ahg,
                                                   const unsigned short* __restrict__ Alg,
                                                   const unsigned short* __restrict__ Bth,
                                                   const unsigned short* __restrict__ Btl,
                                                   float* __restrict__ C,
                                                   unsigned short* __restrict__ Ph,
                                                   unsigned short* __restrict__ Pl,
                                                   const float* __restrict__ bias,
                                                   int M, int K) {
    __shared__ __attribute__((aligned(16))) char ldsAh[8192];
    __shared__ __attribute__((aligned(16))) char ldsAl[8192];
    __shared__ __attribute__((aligned(16))) char ldsBh[8192];
    __shared__ __attribute__((aligned(16))) char ldsBl[8192];
    const int tid = threadIdx.x;
    const int lane = tid & 63, wid = tid >> 6;
    const int quad = lane >> 4, l16 = lane & 15;
    const int rowBase = blockIdx.x * 128;
    const int colBase = blockIdx.y * 128;
    const int wm = (wid & 1) * 64, wn = (wid >> 1) * 64;

    floatx4 acc[4][4] = {};

    const int c0 = wid * 64 + lane;
    const int c1 = c0 + 256;
    const int r0 = ((c0 >> 6) << 4) + (c0 & 15), q0 = (c0 >> 4) & 3;
    const int r1 = ((c1 >> 6) << 4) + (c1 & 15), q1 = (c1 >> 4) & 3;
    const size_t aoff0 = (size_t)(rowBase + r0) * K + q0 * 8;
    const size_t aoff1 = (size_t)(rowBase + r1) * K + q1 * 8;
    const size_t boff0 = (size_t)(colBase + r0) * K + q0 * 8;
    const size_t boff1 = (size_t)(colBase + r1) * K + q1 * 8;
    const int lo0 = (wid * 64) * 16;
    const int lo1 = (256 + wid * 64) * 16;

    for (int k0 = 0; k0 < K; k0 += 32) {
        load_lds16(ldsAh + lo0, Ahg + aoff0 + k0);
        load_lds16(ldsAh + lo1, Ahg + aoff1 + k0);
        load_lds16(ldsAl + lo0, Alg + aoff0 + k0);
        load_lds16(ldsAl + lo1, Alg + aoff1 + k0);
        load_lds16(ldsBh + lo0, Bth + boff0 + k0);
        load_lds16(ldsBh + lo1, Bth + boff1 + k0);
        load_lds16(ldsBl + lo0, Btl + boff0 + k0);
        load_lds16(ldsBl + lo1, Btl + boff1 + k0);
        __syncthreads();

        const short8* vAh = (const short8*)ldsAh;
        const short8* vAl = (const short8*)ldsAl;
        const short8* vBh = (const short8*)ldsBh;
        const short8* vBl = (const short8*)ldsBl;
        short8 afh[4], afl[4], bfh[4], bfl[4];
#pragma unroll
        for (int mi = 0; mi < 4; ++mi) {
            int idx = ((wm >> 4) + mi) * 64 + quad * 16 + l16;
            afh[mi] = vAh[idx];
            afl[mi] = vAl[idx];
        }
#pragma unroll
        for (int ni = 0; ni < 4; ++ni) {
            int idx = ((wn >> 4) + ni) * 64 + quad * 16 + l16;
            bfh[ni] = vBh[idx];
            bfl[ni] = vBl[idx];
        }
#pragma unroll
        for (int mi = 0; mi < 4; ++mi)
#pragma unroll
            for (int ni = 0; ni < 4; ++ni) {
                acc[mi][ni] = __builtin_amdgcn_mfma_f32_16x16x32_bf16(afh[mi], bfh[ni], acc[mi][ni], 0, 0, 0);
                acc[mi][ni] = __builtin_amdgcn_mfma_f32_16x16x32_bf16(afh[mi], bfl[ni], acc[mi][ni], 0, 0, 0);
                acc[mi][ni] = __builtin_amdgcn_mfma_f32_16x16x32_bf16(afl[mi], bfh[ni], acc[mi][ni], 0, 0, 0);
            }
        __syncthreads();
    }

    // C/D layout: col=l16, row=quad*4+reg
#pragma unroll
    for (int mi = 0; mi < 4; ++mi) {
#pragma unroll
        for (int r = 0; r < 4; ++r) {
            int grow = rowBase + wm + mi * 16 + quad * 4 + r;
            if (grow < M) {
                if (SPLIT) {
#pragma unroll
                    for (int ni = 0; ni < 4; ++ni) {
                        int gcol = colBase + wn + ni * 16 + l16;
                        float v = acc[mi][ni][r] + bias[gcol];
                        v = fmaxf(v, 0.f);
                        unsigned short h = bf16_rne(v);
                        unsigned short l = bf16_rne(v - __uint_as_float((unsigned)h << 16));
                        Ph[(size_t)grow * 256 + gcol] = h;
                        Pl[(size_t)grow * 256 + gcol] = l;
                    }
                } else {
#pragma unroll
                    for (int ni = 0; ni < 4; ++ni)
                        C[(size_t)grow * 256 + colBase + wn + ni * 16 + l16] = acc[mi][ni][r];
                }
            }
        }
    }
}

// ---------------- FC: out[M,40] = relu(X[M,256]) @ W[256,40] + b ----------------
__global__ __launch_bounds__(256) void k_fc(float* __restrict__ out, const float* __restrict__ X,
                                            const float* __restrict__ W, const float* __restrict__ bias,
                                            int M) {
    __shared__ float Ws[256 * 40];
    __shared__ float Xs[32][68];
    const int tid = threadIdx.x;
#pragma unroll
    for (int t = 0; t < 10; ++t) {
        int idx = (t * 256 + tid) * 4;
        *reinterpret_cast<float4*>(&Ws[idx]) = *reinterpret_cast<const float4*>(W + idx);
    }
    const int rowBase = blockIdx.x * 64;
    const int r  = tid >> 2;
    const int cg = (tid & 3) * 10;
    const int ar = tid >> 3, ac = (tid & 7) << 2;
    float acc[10] = {};

    for (int k0 = 0; k0 < 256; k0 += 32) {
#pragma unroll
        for (int h = 0; h < 2; ++h) {
            int rr = rowBase + ar + h * 32;
            float4 v = make_float4(0.f, 0.f, 0.f, 0.f);
            if (rr < M) v = *reinterpret_cast<const float4*>(X + (size_t)rr * 256 + k0 + ac);
            v.x = fmaxf(v.x, 0.f); v.y = fmaxf(v.y, 0.f);
            v.z = fmaxf(v.z, 0.f); v.w = fmaxf(v.w, 0.f);
            Xs[ac + 0][ar + h * 32] = v.x;
            Xs[ac + 1][ar + h * 32] = v.y;
            Xs[ac + 2][ar + h * 32] = v.z;
            Xs[ac + 3][ar + h * 32] = v.w;
        }
        __syncthreads();
#pragma unroll
        for (int kk = 0; kk < 32; ++kk) {
            float xv = Xs[kk][r];
#pragma unroll
            for (int j = 0; j < 10; ++j)
                acc[j] = fmaf(xv, Ws[(k0 + kk) * 40 + cg + j], acc[j]);
        }
        __syncthreads();
    }

    int orow = rowBase + r;
    if (orow < M) {
#pragma unroll
        for (int j = 0; j < 10; ++j)
            out[(size_t)orow * 40 + cg + j] = acc[j] + bias[cg + j];
    }
}

extern "C" void kernel_launch(void* const* d_in, const int* in_sizes, int n_in,
                              void* d_out, int out_size, void* d_ws, size_t ws_size,
                              hipStream_t stream) {
    const float* x   = (const float*)d_in[0];
    const int*   ei  = (const int*)d_in[1];
    const float* ea  = (const float*)d_in[2];
    const float* W1  = (const float*)d_in[3];
    const float* b1  = (const float*)d_in[4];
    const float* W2  = (const float*)d_in[5];
    const float* b2  = (const float*)d_in[6];
    const float* fcW = (const float*)d_in[7];
    const float* fcb = (const float*)d_in[8];
    float* out = (float*)d_out;

    const int n = NODES, e = EDGES;
    const int* row = ei;
    const int* col = ei + e;

    char* ws = (char*)d_ws;
    char*  Areg   = ws;                                        // 102,400,000 B
    char*  Breg   = ws + 102400000u;                           // 102,400,000 B
    float* dinv   = (float*)(ws + 204800000u);                 // 400,000 B
    int*   cnt    = (int*)  (ws + 205200000u);                 // 400,000 B (cursor)
    int*   rowptr = (int*)  (ws + 205600000u);                 // 400,016 B
    int2*  meta   = (int2*) (ws + 206000016u);                 // 12,800,000 B
    unsigned short* W1th = (unsigned short*)(ws + 218800016u); // 65,536 B
    unsigned short* W1tl = (unsigned short*)(ws + 218865552u); // 65,536 B
    unsigned short* W2th = (unsigned short*)(ws + 218931088u); // 131,072 B
    unsigned short* W2tl = (unsigned short*)(ws + 219062160u); // 131,072 B
    int* partials = (int*)(ws + 219193232u);                   // ~1.6 KB -> ends ~219,194,800

    // overlays (time-shared):
    unsigned short* Xah = (unsigned short*)Areg;               // 25.6 MB (agg(x) hi)  [phase 1]
    unsigned short* Xal = (unsigned short*)(Areg + 25600000u); // 25.6 MB (agg(x) lo)
    float* H2 = (float*)Areg;                                  // 102.4 MB (GEMM2 out) [phase 2]
    unsigned short* Ph = (unsigned short*)Breg;                // 51.2 MB (relu(P1) hi)
    unsigned short* Pl = (unsigned short*)(Breg + 51200000u);  // 51.2 MB (relu(P1) lo)
    float* P2 = (float*)Breg;                                  // 102.4 MB (gather2 out) [phase 3]

    const int nb = (n + 255) / 256;   // 391
    const int eb = e / 256;           // 6250

    // ---- norm + CSR build ----
    k_init<<<nb, 256, 0, stream>>>(dinv, cnt, n);
    k_deg_hist<<<eb, 256, 0, stream>>>(dinv, cnt, col, ea, e);
    k_scan1<<<nb, 256, 0, stream>>>(cnt, rowptr, partials, dinv, n);
    k_scan2<<<1, 512, 0, stream>>>(partials, nb);
    k_scan3<<<nb, 256, 0, stream>>>(rowptr, cnt, partials, n);
    k_build<<<eb, 256, 0, stream>>>(cnt, meta, row, col, ea, dinv, e);
    k_splitB<<<128, 256, 0, stream>>>(W1, W1th, W1tl, 128);
    k_splitB<<<256, 256, 0, stream>>>(W2, W2th, W2tl, 256);

    dim3 gg((n + 127) / 128, 2);

    // layer 1 (agg-first): Xagg = agg(x) [128ch, bf16-split] ; P1relu = relu(Xagg@W1 + b1) [bf16-split]
    k_gather_x<<<(n + 3) / 4, 256, 0, stream>>>(Xah, Xal, x, dinv, rowptr, meta, n);
    k_gemm_bf16<true><<<gg, 256, 0, stream>>>(Xah, Xal, W1th, W1tl, nullptr, Ph, Pl, b1, n, 128);

    // layer 2: H2 = relu(P1) @ W2 ; P2 = agg(H2) + b2
    k_gemm_bf16<false><<<gg, 256, 0, stream>>>(Ph, Pl, W2th, W2tl, H2, nullptr, nullptr, nullptr, n, 256);
    k_gather<<<(n + 3) / 4, 256, 0, stream>>>(P2, H2, dinv, rowptr, meta, b2, n);

    // classifier
    k_fc<<<(n + 63) / 64, 256, 0, stream>>>(out, P2, fcW, fcb, n);
}

// Round 6
// 774.139 us; speedup vs baseline: 14.4334x; 1.1997x over previous
//
#include <hip/hip_runtime.h>

#define NODES 100000
#define EDGES 1600000

typedef __attribute__((ext_vector_type(8))) short short8;
typedef __attribute__((ext_vector_type(4))) float floatx4;
typedef _Float16 h16;
typedef __attribute__((ext_vector_type(2))) _Float16 h16x2;
typedef __attribute__((ext_vector_type(4))) _Float16 h16x4;

__device__ inline unsigned short bf16_rne(float x) {
    unsigned u = __float_as_uint(x);
    u += 0x7FFF + ((u >> 16) & 1);
    return (unsigned short)(u >> 16);
}

__device__ inline void load_lds16(void* lds, const void* g) {
    __builtin_amdgcn_global_load_lds((const __attribute__((address_space(1))) void*)g,
                                     (__attribute__((address_space(3))) void*)lds, 16, 0, 0);
}

// ---------------- init / degree ----------------
__global__ __launch_bounds__(256) void k_init(float* __restrict__ deg, int* __restrict__ cnt, int n) {
    int i = blockIdx.x * 256 + threadIdx.x;
    if (i < n) { deg[i] = 1.0f; cnt[i] = 0; }
}

__global__ __launch_bounds__(256) void k_deg_hist(float* __restrict__ deg, int* __restrict__ cnt,
                                                  const int* __restrict__ col,
                                                  const float* __restrict__ ew, int e) {
    int i = blockIdx.x * 256 + threadIdx.x;
    if (i < e) {
        int c = col[i];
        atomicAdd(&deg[c], ew[i]);
        atomicAdd(&cnt[c], 1);
    }
}

// ---------------- scan phase 1 (+ fused dinv) ----------------
__global__ __launch_bounds__(256) void k_scan1(const int* __restrict__ cnt, int* __restrict__ rowptr,
                                               int* __restrict__ partials, float* __restrict__ deg, int n) {
    __shared__ int wtot[4];
    const int tid = threadIdx.x, lane = tid & 63, wid = tid >> 6;
    int i = blockIdx.x * 256 + tid;
    if (i < n) deg[i] = rsqrtf(deg[i]);
    int v = (i < n) ? cnt[i] : 0;
    int incl = v;
#pragma unroll
    for (int off = 1; off < 64; off <<= 1) {
        int t = __shfl_up(incl, off, 64);
        if (lane >= off) incl += t;
    }
    if (lane == 63) wtot[wid] = incl;
    __syncthreads();
    int woff = 0;
    for (int k = 0; k < wid; ++k) woff += wtot[k];
    if (i < n) rowptr[i] = woff + incl - v;
    if (tid == 255) partials[blockIdx.x] = woff + incl;
}

__global__ __launch_bounds__(512) void k_scan2(int* __restrict__ partials, int nb) {
    __shared__ int wtot[8];
    const int tid = threadIdx.x, lane = tid & 63, wid = tid >> 6;
    int v = (tid < nb) ? partials[tid] : 0;
    int incl = v;
#pragma unroll
    for (int off = 1; off < 64; off <<= 1) {
        int t = __shfl_up(incl, off, 64);
        if (lane >= off) incl += t;
    }
    if (lane == 63) wtot[wid] = incl;
    __syncthreads();
    int woff = 0;
    for (int k = 0; k < wid; ++k) woff += wtot[k];
    if (tid < nb) partials[tid] = woff + incl - v;
}

__global__ __launch_bounds__(256) void k_scan3(int* __restrict__ rowptr, int* __restrict__ cursor,
                                               const int* __restrict__ partials, int n) {
    int i = blockIdx.x * 256 + threadIdx.x;
    if (i < n) {
        int v = rowptr[i] + partials[blockIdx.x];
        rowptr[i] = v;
        cursor[i] = v;
    }
    if (blockIdx.x == 0 && threadIdx.x == 0) rowptr[n] = EDGES;
}

__global__ __launch_bounds__(256) void k_build(int* __restrict__ cursor, int2* __restrict__ meta,
                                               const int* __restrict__ row, const int* __restrict__ col,
                                               const float* __restrict__ ew,
                                               const float* __restrict__ dinv, int e) {
    int i = blockIdx.x * 256 + threadIdx.x;
    if (i >= e) return;
    int r = row[i], c = col[i];
    float w = dinv[r] * ew[i] * dinv[c];
    int pos = atomicAdd(&cursor[c], 1);
    meta[pos] = make_int2(r, __float_as_int(w));
}

// ---------------- x -> fp16 copy ----------------
__global__ __launch_bounds__(256) void k_half_x(const float* __restrict__ X, h16* __restrict__ X16, int total4) {
    int i = blockIdx.x * 256 + threadIdx.x;
    if (i >= total4) return;
    float4 v = reinterpret_cast<const float4*>(X)[i];
    h16x4 h;
    h.x = (h16)v.x; h.y = (h16)v.y; h.z = (h16)v.z; h.w = (h16)v.w;
    reinterpret_cast<h16x4*>(X16)[i] = h;
}

// ---------------- gather on fp16 x (128 ch): Xagg = agg(x), epilogue bf16 split ----------------
__global__ __launch_bounds__(256) void k_gather_x(unsigned short* __restrict__ Xh,
                                                  unsigned short* __restrict__ Xl,
                                                  const h16* __restrict__ x16,
                                                  const float* __restrict__ dinv,
                                                  const int* __restrict__ rowptr,
                                                  const int2* __restrict__ meta, int n) {
    int node = (blockIdx.x << 2) + (threadIdx.x >> 6);
    if (node >= n) return;
    const int lane = threadIdx.x & 63;
    const int j = lane << 1;
    float di = dinv[node];
    float s = di * di;
    h16x2 xs = *reinterpret_cast<const h16x2*>(x16 + (size_t)node * 128 + j);
    float2 a0 = make_float2((float)xs.x * s, (float)xs.y * s);
    float2 a1 = make_float2(0.f, 0.f);

    int p = rowptr[node];
    const int end = rowptr[node + 1];
    for (; p + 3 < end; p += 4) {
        int2 m0 = meta[p],     m1 = meta[p + 1];
        int2 m2 = meta[p + 2], m3 = meta[p + 3];
        h16x2 h0 = *reinterpret_cast<const h16x2*>(x16 + (size_t)m0.x * 128 + j);
        h16x2 h1 = *reinterpret_cast<const h16x2*>(x16 + (size_t)m1.x * 128 + j);
        h16x2 h2 = *reinterpret_cast<const h16x2*>(x16 + (size_t)m2.x * 128 + j);
        h16x2 h3 = *reinterpret_cast<const h16x2*>(x16 + (size_t)m3.x * 128 + j);
        float w0 = __int_as_float(m0.y), w1 = __int_as_float(m1.y);
        float w2 = __int_as_float(m2.y), w3 = __int_as_float(m3.y);
        a0.x = fmaf((float)h0.x, w0, a0.x); a0.y = fmaf((float)h0.y, w0, a0.y);
        a1.x = fmaf((float)h1.x, w1, a1.x); a1.y = fmaf((float)h1.y, w1, a1.y);
        a0.x = fmaf((float)h2.x, w2, a0.x); a0.y = fmaf((float)h2.y, w2, a0.y);
        a1.x = fmaf((float)h3.x, w3, a1.x); a1.y = fmaf((float)h3.y, w3, a1.y);
    }
    for (; p < end; ++p) {
        int2 m0 = meta[p];
        h16x2 h0 = *reinterpret_cast<const h16x2*>(x16 + (size_t)m0.x * 128 + j);
        float w0 = __int_as_float(m0.y);
        a0.x = fmaf((float)h0.x, w0, a0.x); a0.y = fmaf((float)h0.y, w0, a0.y);
    }
    a0.x += a1.x; a0.y += a1.y;

    ushort2 hh, ll;
    hh.x = bf16_rne(a0.x); ll.x = bf16_rne(a0.x - __uint_as_float((unsigned)hh.x << 16));
    hh.y = bf16_rne(a0.y); ll.y = bf16_rne(a0.y - __uint_as_float((unsigned)hh.y << 16));
    *reinterpret_cast<ushort2*>(Xh + (size_t)node * 128 + j) = hh;
    *reinterpret_cast<ushort2*>(Xl + (size_t)node * 128 + j) = ll;
}

// ---------------- gather-reduce on fp16 H2 (256 ch, + bias) -> fp32 P2 ----------------
__global__ __launch_bounds__(256) void k_gather(float* __restrict__ P,
                                                const h16* __restrict__ H,
                                                const float* __restrict__ dinv,
                                                const int* __restrict__ rowptr,
                                                const int2* __restrict__ meta,
                                                const float* __restrict__ bias, int n) {
    int node = (blockIdx.x << 2) + (threadIdx.x >> 6);
    if (node >= n) return;
    const int lane = threadIdx.x & 63;
    const int j = lane << 2;
    float di = dinv[node];
    float s = di * di;
    float4 b = *reinterpret_cast<const float4*>(bias + j);
    h16x4 hv = *reinterpret_cast<const h16x4*>(H + (size_t)node * 256 + j);
    float4 acc;
    acc.x = fmaf((float)hv.x, s, b.x); acc.y = fmaf((float)hv.y, s, b.y);
    acc.z = fmaf((float)hv.z, s, b.z); acc.w = fmaf((float)hv.w, s, b.w);
    float4 acc2 = make_float4(0.f, 0.f, 0.f, 0.f);

    int p = rowptr[node];
    const int end = rowptr[node + 1];
    for (; p + 3 < end; p += 4) {
        int2 m0 = meta[p],     m1 = meta[p + 1];
        int2 m2 = meta[p + 2], m3 = meta[p + 3];
        h16x4 h0 = *reinterpret_cast<const h16x4*>(H + (size_t)m0.x * 256 + j);
        h16x4 h1 = *reinterpret_cast<const h16x4*>(H + (size_t)m1.x * 256 + j);
        h16x4 h2 = *reinterpret_cast<const h16x4*>(H + (size_t)m2.x * 256 + j);
        h16x4 h3 = *reinterpret_cast<const h16x4*>(H + (size_t)m3.x * 256 + j);
        float w0 = __int_as_float(m0.y), w1 = __int_as_float(m1.y);
        float w2 = __int_as_float(m2.y), w3 = __int_as_float(m3.y);
        acc.x  = fmaf((float)h0.x, w0, acc.x);  acc.y  = fmaf((float)h0.y, w0, acc.y);
        acc.z  = fmaf((float)h0.z, w0, acc.z);  acc.w  = fmaf((float)h0.w, w0, acc.w);
        acc2.x = fmaf((float)h1.x, w1, acc2.x); acc2.y = fmaf((float)h1.y, w1, acc2.y);
        acc2.z = fmaf((float)h1.z, w1, acc2.z); acc2.w = fmaf((float)h1.w, w1, acc2.w);
        acc.x  = fmaf((float)h2.x, w2, acc.x);  acc.y  = fmaf((float)h2.y, w2, acc.y);
        acc.z  = fmaf((float)h2.z, w2, acc.z);  acc.w  = fmaf((float)h2.w, w2, acc.w);
        acc2.x = fmaf((float)h3.x, w3, acc2.x); acc2.y = fmaf((float)h3.y, w3, acc2.y);
        acc2.z = fmaf((float)h3.z, w3, acc2.z); acc2.w = fmaf((float)h3.w, w3, acc2.w);
    }
    for (; p < end; ++p) {
        int2 m0 = meta[p];
        h16x4 h0 = *reinterpret_cast<const h16x4*>(H + (size_t)m0.x * 256 + j);
        float w0 = __int_as_float(m0.y);
        acc.x = fmaf((float)h0.x, w0, acc.x); acc.y = fmaf((float)h0.y, w0, acc.y);
        acc.z = fmaf((float)h0.z, w0, acc.z); acc.w = fmaf((float)h0.w, w0, acc.w);
    }
    acc.x += acc2.x; acc.y += acc2.y; acc.z += acc2.z; acc.w += acc2.w;
    *reinterpret_cast<float4*>(P + (size_t)node * 256 + j) = acc;
}

// ---------------- W split+transpose: W[K,256] -> [256,K] bf16 hi/lo ----------------
__global__ __launch_bounds__(256) void k_splitB(const float* __restrict__ W,
                                                unsigned short* __restrict__ Bth,
                                                unsigned short* __restrict__ Btl, int K) {
    int idx = blockIdx.x * 256 + threadIdx.x;
    if (idx >= K * 256) return;
    int k = idx >> 8, nn = idx & 255;
    float v = W[idx];
    unsigned short h = bf16_rne(v);
    float hf = __uint_as_float((unsigned)h << 16);
    unsigned short l = bf16_rne(v - hf);
    Bth[nn * K + k] = h;
    Btl[nn * K + k] = l;
}

// ---------------- split-bf16 MFMA GEMM ----------------
// C ~= Ah@Bh^T + Ah@Bl^T + Al@Bh^T ; A [M,K] bf16, B [256,K] bf16.
// SPLIT: epilogue +bias, relu, bf16 hi/lo -> Ph/Pl.  else: fp16 -> Hh.
template<bool SPLIT>
__global__ __launch_bounds__(256) void k_gemm_bf16(const unsigned short* __restrict__ Ahg,
                                                   const unsigned short* __restrict__ Alg,
                                                   const unsigned short* __restrict__ Bth,
                                                   const unsigned short* __restrict__ Btl,
                                                   h16* __restrict__ Hh,
                                                   unsigned short* __restrict__ Ph,
                                                   unsigned short* __restrict__ Pl,
                                                   const float* __restrict__ bias,
                                                   int M, int K) {
    __shared__ __attribute__((aligned(16))) char ldsAh[8192];
    __shared__ __attribute__((aligned(16))) char ldsAl[8192];
    __shared__ __attribute__((aligned(16))) char ldsBh[8192];
    __shared__ __attribute__((aligned(16))) char ldsBl[8192];
    const int tid = threadIdx.x;
    const int lane = tid & 63, wid = tid >> 6;
    const int quad = lane >> 4, l16 = lane & 15;
    const int rowBase = blockIdx.x * 128;
    const int colBase = blockIdx.y * 128;
    const int wm = (wid & 1) * 64, wn = (wid >> 1) * 64;

    floatx4 acc[4][4] = {};

    const int c0 = wid * 64 + lane;
    const int c1 = c0 + 256;
    const int r0 = ((c0 >> 6) << 4) + (c0 & 15), q0 = (c0 >> 4) & 3;
    const int r1 = ((c1 >> 6) << 4) + (c1 & 15), q1 = (c1 >> 4) & 3;
    const size_t aoff0 = (size_t)(rowBase + r0) * K + q0 * 8;
    const size_t aoff1 = (size_t)(rowBase + r1) * K + q1 * 8;
    const size_t boff0 = (size_t)(colBase + r0) * K + q0 * 8;
    const size_t boff1 = (size_t)(colBase + r1) * K + q1 * 8;
    const int lo0 = (wid * 64) * 16;
    const int lo1 = (256 + wid * 64) * 16;

    for (int k0 = 0; k0 < K; k0 += 32) {
        load_lds16(ldsAh + lo0, Ahg + aoff0 + k0);
        load_lds16(ldsAh + lo1, Ahg + aoff1 + k0);
        load_lds16(ldsAl + lo0, Alg + aoff0 + k0);
        load_lds16(ldsAl + lo1, Alg + aoff1 + k0);
        load_lds16(ldsBh + lo0, Bth + boff0 + k0);
        load_lds16(ldsBh + lo1, Bth + boff1 + k0);
        load_lds16(ldsBl + lo0, Btl + boff0 + k0);
        load_lds16(ldsBl + lo1, Btl + boff1 + k0);
        __syncthreads();

        const short8* vAh = (const short8*)ldsAh;
        const short8* vAl = (const short8*)ldsAl;
        const short8* vBh = (const short8*)ldsBh;
        const short8* vBl = (const short8*)ldsBl;
        short8 afh[4], afl[4], bfh[4], bfl[4];
#pragma unroll
        for (int mi = 0; mi < 4; ++mi) {
            int idx = ((wm >> 4) + mi) * 64 + quad * 16 + l16;
            afh[mi] = vAh[idx];
            afl[mi] = vAl[idx];
        }
#pragma unroll
        for (int ni = 0; ni < 4; ++ni) {
            int idx = ((wn >> 4) + ni) * 64 + quad * 16 + l16;
            bfh[ni] = vBh[idx];
            bfl[ni] = vBl[idx];
        }
#pragma unroll
        for (int mi = 0; mi < 4; ++mi)
#pragma unroll
            for (int ni = 0; ni < 4; ++ni) {
                acc[mi][ni] = __builtin_amdgcn_mfma_f32_16x16x32_bf16(afh[mi], bfh[ni], acc[mi][ni], 0, 0, 0);
                acc[mi][ni] = __builtin_amdgcn_mfma_f32_16x16x32_bf16(afh[mi], bfl[ni], acc[mi][ni], 0, 0, 0);
                acc[mi][ni] = __builtin_amdgcn_mfma_f32_16x16x32_bf16(afl[mi], bfh[ni], acc[mi][ni], 0, 0, 0);
            }
        __syncthreads();
    }

    // C/D layout: col=l16, row=quad*4+reg
#pragma unroll
    for (int mi = 0; mi < 4; ++mi) {
#pragma unroll
        for (int r = 0; r < 4; ++r) {
            int grow = rowBase + wm + mi * 16 + quad * 4 + r;
            if (grow < M) {
                if (SPLIT) {
#pragma unroll
                    for (int ni = 0; ni < 4; ++ni) {
                        int gcol = colBase + wn + ni * 16 + l16;
                        float v = acc[mi][ni][r] + bias[gcol];
                        v = fmaxf(v, 0.f);
                        unsigned short h = bf16_rne(v);
                        unsigned short l = bf16_rne(v - __uint_as_float((unsigned)h << 16));
                        Ph[(size_t)grow * 256 + gcol] = h;
                        Pl[(size_t)grow * 256 + gcol] = l;
                    }
                } else {
#pragma unroll
                    for (int ni = 0; ni < 4; ++ni)
                        Hh[(size_t)grow * 256 + colBase + wn + ni * 16 + l16] = (h16)acc[mi][ni][r];
                }
            }
        }
    }
}

// ---------------- FC: out[M,40] = relu(X[M,256]) @ W[256,40] + b ----------------
__global__ __launch_bounds__(256) void k_fc(float* __restrict__ out, const float* __restrict__ X,
                                            const float* __restrict__ W, const float* __restrict__ bias,
                                            int M) {
    __shared__ float Ws[256 * 40];
    __shared__ float Xs[32][68];
    const int tid = threadIdx.x;
#pragma unroll
    for (int t = 0; t < 10; ++t) {
        int idx = (t * 256 + tid) * 4;
        *reinterpret_cast<float4*>(&Ws[idx]) = *reinterpret_cast<const float4*>(W + idx);
    }
    const int rowBase = blockIdx.x * 64;
    const int r  = tid >> 2;
    const int cg = (tid & 3) * 10;
    const int ar = tid >> 3, ac = (tid & 7) << 2;
    float acc[10] = {};

    for (int k0 = 0; k0 < 256; k0 += 32) {
#pragma unroll
        for (int h = 0; h < 2; ++h) {
            int rr = rowBase + ar + h * 32;
            float4 v = make_float4(0.f, 0.f, 0.f, 0.f);
            if (rr < M) v = *reinterpret_cast<const float4*>(X + (size_t)rr * 256 + k0 + ac);
            v.x = fmaxf(v.x, 0.f); v.y = fmaxf(v.y, 0.f);
            v.z = fmaxf(v.z, 0.f); v.w = fmaxf(v.w, 0.f);
            Xs[ac + 0][ar + h * 32] = v.x;
            Xs[ac + 1][ar + h * 32] = v.y;
            Xs[ac + 2][ar + h * 32] = v.z;
            Xs[ac + 3][ar + h * 32] = v.w;
        }
        __syncthreads();
#pragma unroll
        for (int kk = 0; kk < 32; ++kk) {
            float xv = Xs[kk][r];
#pragma unroll
            for (int j = 0; j < 10; ++j)
                acc[j] = fmaf(xv, Ws[(k0 + kk) * 40 + cg + j], acc[j]);
        }
        __syncthreads();
    }

    int orow = rowBase + r;
    if (orow < M) {
#pragma unroll
        for (int j = 0; j < 10; ++j)
            out[(size_t)orow * 40 + cg + j] = acc[j] + bias[cg + j];
    }
}

extern "C" void kernel_launch(void* const* d_in, const int* in_sizes, int n_in,
                              void* d_out, int out_size, void* d_ws, size_t ws_size,
                              hipStream_t stream) {
    const float* x   = (const float*)d_in[0];
    const int*   ei  = (const int*)d_in[1];
    const float* ea  = (const float*)d_in[2];
    const float* W1  = (const float*)d_in[3];
    const float* b1  = (const float*)d_in[4];
    const float* W2  = (const float*)d_in[5];
    const float* b2  = (const float*)d_in[6];
    const float* fcW = (const float*)d_in[7];
    const float* fcb = (const float*)d_in[8];
    float* out = (float*)d_out;

    const int n = NODES, e = EDGES;
    const int* row = ei;
    const int* col = ei + e;

    char* ws = (char*)d_ws;
    char*  Areg   = ws;                                        // 102,400,000 B
    char*  Breg   = ws + 102400000u;                           // 102,400,000 B
    float* dinv   = (float*)(ws + 204800000u);                 // 400,000 B
    int*   cnt    = (int*)  (ws + 205200000u);                 // 400,000 B (cursor)
    int*   rowptr = (int*)  (ws + 205600000u);                 // 400,016 B
    int2*  meta   = (int2*) (ws + 206000016u);                 // 12,800,000 B
    unsigned short* W1th = (unsigned short*)(ws + 218800016u); // 65,536 B
    unsigned short* W1tl = (unsigned short*)(ws + 218865552u); // 65,536 B
    unsigned short* W2th = (unsigned short*)(ws + 218931088u); // 131,072 B
    unsigned short* W2tl = (unsigned short*)(ws + 219062160u); // 131,072 B
    int* partials = (int*)(ws + 219193232u);                   // ~1.6 KB

    // overlays (time-shared):
    unsigned short* Xah = (unsigned short*)Areg;               // 25.6 MB (agg(x) hi)   [phase 1]
    unsigned short* Xal = (unsigned short*)(Areg + 25600000u); // 25.6 MB (agg(x) lo)
    h16* x16 = (h16*)(Areg + 51200000u);                       // 25.6 MB (fp16 x)      [phase 1]
    h16* H2h = (h16*)Areg;                                     // 51.2 MB (GEMM2 out)   [phase 2]
    unsigned short* Ph = (unsigned short*)Breg;                // 51.2 MB (relu(P1) hi)
    unsigned short* Pl = (unsigned short*)(Breg + 51200000u);  // 51.2 MB (relu(P1) lo)
    float* P2 = (float*)Breg;                                  // 102.4 MB (gather2 out)[phase 3]

    const int nb = (n + 255) / 256;   // 391
    const int eb = e / 256;           // 6250

    // ---- norm + CSR build ----
    k_init<<<nb, 256, 0, stream>>>(dinv, cnt, n);
    k_deg_hist<<<eb, 256, 0, stream>>>(dinv, cnt, col, ea, e);
    k_scan1<<<nb, 256, 0, stream>>>(cnt, rowptr, partials, dinv, n);
    k_scan2<<<1, 512, 0, stream>>>(partials, nb);
    k_scan3<<<nb, 256, 0, stream>>>(rowptr, cnt, partials, n);
    k_build<<<eb, 256, 0, stream>>>(cnt, meta, row, col, ea, dinv, e);
    k_splitB<<<128, 256, 0, stream>>>(W1, W1th, W1tl, 128);
    k_splitB<<<256, 256, 0, stream>>>(W2, W2th, W2tl, 256);
    k_half_x<<<(n * 32 + 255) / 256, 256, 0, stream>>>(x, x16, n * 32);

    dim3 gg((n + 127) / 128, 2);

    // layer 1 (agg-first): Xagg = agg(x16) [bf16-split] ; P1relu = relu(Xagg@W1 + b1) [bf16-split]
    k_gather_x<<<(n + 3) / 4, 256, 0, stream>>>(Xah, Xal, x16, dinv, rowptr, meta, n);
    k_gemm_bf16<true><<<gg, 256, 0, stream>>>(Xah, Xal, W1th, W1tl, nullptr, Ph, Pl, b1, n, 128);

    // layer 2: H2 = relu(P1) @ W2 [fp16] ; P2 = agg(H2) + b2 [fp32]
    k_gemm_bf16<false><<<gg, 256, 0, stream>>>(Ph, Pl, W2th, W2tl, H2h, nullptr, nullptr, nullptr, n, 256);
    k_gather<<<(n + 3) / 4, 256, 0, stream>>>(P2, H2h, dinv, rowptr, meta, b2, n);

    // classifier
    k_fc<<<(n + 63) / 64, 256, 0, stream>>>(out, P2, fcW, fcb, n);
}

// Round 7
// 701.090 us; speedup vs baseline: 15.9372x; 1.1042x over previous
//
#include <hip/hip_runtime.h>

#define NODES 100000
#define EDGES 1600000

typedef __attribute__((ext_vector_type(8))) short short8;
typedef __attribute__((ext_vector_type(4))) float floatx4;
typedef _Float16 h16;
typedef __attribute__((ext_vector_type(2))) _Float16 h16x2;
typedef __attribute__((ext_vector_type(4))) _Float16 h16x4;

__device__ inline unsigned short bf16_rne(float x) {
    unsigned u = __float_as_uint(x);
    u += 0x7FFF + ((u >> 16) & 1);
    return (unsigned short)(u >> 16);
}

__device__ inline void load_lds16(void* lds, const void* g) {
    __builtin_amdgcn_global_load_lds((const __attribute__((address_space(1))) void*)g,
                                     (__attribute__((address_space(3))) void*)lds, 16, 0, 0);
}

// ---------------- init packed degree/count accumulator ----------------
__global__ __launch_bounds__(256) void k_init(unsigned long long* __restrict__ packed, int n) {
    int i = blockIdx.x * 256 + threadIdx.x;
    if (i < n) packed[i] = 0ull;
}

// ---------------- packed histogram: one 64b atomic = (cnt<<40) | fix20(ew) ----------------
__global__ __launch_bounds__(256) void k_hist(unsigned long long* __restrict__ packed,
                                              const int* __restrict__ col,
                                              const float* __restrict__ ew, int e) {
    int i = blockIdx.x * 256 + threadIdx.x;
    if (i < e) {
        int c = col[i];
        unsigned long long v = (1ull << 40) |
            (unsigned long long)__float2uint_rn(ew[i] * 1048576.0f);
        atomicAdd(&packed[c], v);
    }
}

// ---------------- scan phase 1: unpack cnt, compute dinv, block-scan ----------------
__global__ __launch_bounds__(256) void k_scan1(const unsigned long long* __restrict__ packed,
                                               int* __restrict__ rowptr,
                                               int* __restrict__ partials,
                                               float* __restrict__ dinv, int n) {
    __shared__ int wtot[4];
    const int tid = threadIdx.x, lane = tid & 63, wid = tid >> 6;
    int i = blockIdx.x * 256 + tid;
    int v = 0;
    if (i < n) {
        unsigned long long p = packed[i];
        v = (int)(p >> 40);
        float deg = 1.0f + (float)(p & 0xFFFFFFFFFFull) * (1.0f / 1048576.0f);
        dinv[i] = rsqrtf(deg);
    }
    int incl = v;
#pragma unroll
    for (int off = 1; off < 64; off <<= 1) {
        int t = __shfl_up(incl, off, 64);
        if (lane >= off) incl += t;
    }
    if (lane == 63) wtot[wid] = incl;
    __syncthreads();
    int woff = 0;
    for (int k = 0; k < wid; ++k) woff += wtot[k];
    if (i < n) rowptr[i] = woff + incl - v;
    if (tid == 255) partials[blockIdx.x] = woff + incl;
}

__global__ __launch_bounds__(512) void k_scan2(int* __restrict__ partials, int nb) {
    __shared__ int wtot[8];
    const int tid = threadIdx.x, lane = tid & 63, wid = tid >> 6;
    int v = (tid < nb) ? partials[tid] : 0;
    int incl = v;
#pragma unroll
    for (int off = 1; off < 64; off <<= 1) {
        int t = __shfl_up(incl, off, 64);
        if (lane >= off) incl += t;
    }
    if (lane == 63) wtot[wid] = incl;
    __syncthreads();
    int woff = 0;
    for (int k = 0; k < wid; ++k) woff += wtot[k];
    if (tid < nb) partials[tid] = woff + incl - v;
}

__global__ __launch_bounds__(256) void k_scan3(int* __restrict__ rowptr, int* __restrict__ cursor,
                                               const int* __restrict__ partials, int n) {
    int i = blockIdx.x * 256 + threadIdx.x;
    if (i < n) {
        int v = rowptr[i] + partials[blockIdx.x];
        rowptr[i] = v;
        cursor[i] = v;
    }
    if (blockIdx.x == 0 && threadIdx.x == 0) rowptr[n] = EDGES;
}

__global__ __launch_bounds__(256) void k_build(int* __restrict__ cursor, int2* __restrict__ meta,
                                               const int* __restrict__ row, const int* __restrict__ col,
                                               const float* __restrict__ ew,
                                               const float* __restrict__ dinv, int e) {
    int i = blockIdx.x * 256 + threadIdx.x;
    if (i >= e) return;
    int r = row[i], c = col[i];
    float w = dinv[r] * ew[i] * dinv[c];
    int pos = atomicAdd(&cursor[c], 1);
    meta[pos] = make_int2(r, __float_as_int(w));
}

// ---------------- x -> fp16 copy ----------------
__global__ __launch_bounds__(256) void k_half_x(const float* __restrict__ X, h16* __restrict__ X16, int total4) {
    int i = blockIdx.x * 256 + threadIdx.x;
    if (i >= total4) return;
    float4 v = reinterpret_cast<const float4*>(X)[i];
    h16x4 h;
    h.x = (h16)v.x; h.y = (h16)v.y; h.z = (h16)v.z; h.w = (h16)v.w;
    reinterpret_cast<h16x4*>(X16)[i] = h;
}

// ---------------- gather on fp16 x (128 ch): Xagg = agg(x), epilogue bf16 split ----------------
__global__ __launch_bounds__(256) void k_gather_x(unsigned short* __restrict__ Xh,
                                                  unsigned short* __restrict__ Xl,
                                                  const h16* __restrict__ x16,
                                                  const float* __restrict__ dinv,
                                                  const int* __restrict__ rowptr,
                                                  const int2* __restrict__ meta, int n) {
    int node = (blockIdx.x << 2) + (threadIdx.x >> 6);
    if (node >= n) return;
    const int lane = threadIdx.x & 63;
    const int j = lane << 1;
    float di = dinv[node];
    float s = di * di;
    h16x2 xs = *reinterpret_cast<const h16x2*>(x16 + (size_t)node * 128 + j);
    float2 a0 = make_float2((float)xs.x * s, (float)xs.y * s);
    float2 a1 = make_float2(0.f, 0.f);

    int p = rowptr[node];
    const int end = rowptr[node + 1];
    for (; p + 3 < end; p += 4) {
        int2 m0 = meta[p],     m1 = meta[p + 1];
        int2 m2 = meta[p + 2], m3 = meta[p + 3];
        h16x2 h0 = *reinterpret_cast<const h16x2*>(x16 + (size_t)m0.x * 128 + j);
        h16x2 h1 = *reinterpret_cast<const h16x2*>(x16 + (size_t)m1.x * 128 + j);
        h16x2 h2 = *reinterpret_cast<const h16x2*>(x16 + (size_t)m2.x * 128 + j);
        h16x2 h3 = *reinterpret_cast<const h16x2*>(x16 + (size_t)m3.x * 128 + j);
        float w0 = __int_as_float(m0.y), w1 = __int_as_float(m1.y);
        float w2 = __int_as_float(m2.y), w3 = __int_as_float(m3.y);
        a0.x = fmaf((float)h0.x, w0, a0.x); a0.y = fmaf((float)h0.y, w0, a0.y);
        a1.x = fmaf((float)h1.x, w1, a1.x); a1.y = fmaf((float)h1.y, w1, a1.y);
        a0.x = fmaf((float)h2.x, w2, a0.x); a0.y = fmaf((float)h2.y, w2, a0.y);
        a1.x = fmaf((float)h3.x, w3, a1.x); a1.y = fmaf((float)h3.y, w3, a1.y);
    }
    for (; p < end; ++p) {
        int2 m0 = meta[p];
        h16x2 h0 = *reinterpret_cast<const h16x2*>(x16 + (size_t)m0.x * 128 + j);
        float w0 = __int_as_float(m0.y);
        a0.x = fmaf((float)h0.x, w0, a0.x); a0.y = fmaf((float)h0.y, w0, a0.y);
    }
    a0.x += a1.x; a0.y += a1.y;

    ushort2 hh, ll;
    hh.x = bf16_rne(a0.x); ll.x = bf16_rne(a0.x - __uint_as_float((unsigned)hh.x << 16));
    hh.y = bf16_rne(a0.y); ll.y = bf16_rne(a0.y - __uint_as_float((unsigned)hh.y << 16));
    *reinterpret_cast<ushort2*>(Xh + (size_t)node * 128 + j) = hh;
    *reinterpret_cast<ushort2*>(Xl + (size_t)node * 128 + j) = ll;
}

// ---------------- gather-reduce on fp16 H2 (256 ch, + bias) -> fp32 P2 ----------------
__global__ __launch_bounds__(256) void k_gather(float* __restrict__ P,
                                                const h16* __restrict__ H,
                                                const float* __restrict__ dinv,
                                                const int* __restrict__ rowptr,
                                                const int2* __restrict__ meta,
                                                const float* __restrict__ bias, int n) {
    int node = (blockIdx.x << 2) + (threadIdx.x >> 6);
    if (node >= n) return;
    const int lane = threadIdx.x & 63;
    const int j = lane << 2;
    float di = dinv[node];
    float s = di * di;
    float4 b = *reinterpret_cast<const float4*>(bias + j);
    h16x4 hv = *reinterpret_cast<const h16x4*>(H + (size_t)node * 256 + j);
    float4 acc;
    acc.x = fmaf((float)hv.x, s, b.x); acc.y = fmaf((float)hv.y, s, b.y);
    acc.z = fmaf((float)hv.z, s, b.z); acc.w = fmaf((float)hv.w, s, b.w);
    float4 acc2 = make_float4(0.f, 0.f, 0.f, 0.f);

    int p = rowptr[node];
    const int end = rowptr[node + 1];
    for (; p + 3 < end; p += 4) {
        int2 m0 = meta[p],     m1 = meta[p + 1];
        int2 m2 = meta[p + 2], m3 = meta[p + 3];
        h16x4 h0 = *reinterpret_cast<const h16x4*>(H + (size_t)m0.x * 256 + j);
        h16x4 h1 = *reinterpret_cast<const h16x4*>(H + (size_t)m1.x * 256 + j);
        h16x4 h2 = *reinterpret_cast<const h16x4*>(H + (size_t)m2.x * 256 + j);
        h16x4 h3 = *reinterpret_cast<const h16x4*>(H + (size_t)m3.x * 256 + j);
        float w0 = __int_as_float(m0.y), w1 = __int_as_float(m1.y);
        float w2 = __int_as_float(m2.y), w3 = __int_as_float(m3.y);
        acc.x  = fmaf((float)h0.x, w0, acc.x);  acc.y  = fmaf((float)h0.y, w0, acc.y);
        acc.z  = fmaf((float)h0.z, w0, acc.z);  acc.w  = fmaf((float)h0.w, w0, acc.w);
        acc2.x = fmaf((float)h1.x, w1, acc2.x); acc2.y = fmaf((float)h1.y, w1, acc2.y);
        acc2.z = fmaf((float)h1.z, w1, acc2.z); acc2.w = fmaf((float)h1.w, w1, acc2.w);
        acc.x  = fmaf((float)h2.x, w2, acc.x);  acc.y  = fmaf((float)h2.y, w2, acc.y);
        acc.z  = fmaf((float)h2.z, w2, acc.z);  acc.w  = fmaf((float)h2.w, w2, acc.w);
        acc2.x = fmaf((float)h3.x, w3, acc2.x); acc2.y = fmaf((float)h3.y, w3, acc2.y);
        acc2.z = fmaf((float)h3.z, w3, acc2.z); acc2.w = fmaf((float)h3.w, w3, acc2.w);
    }
    for (; p < end; ++p) {
        int2 m0 = meta[p];
        h16x4 h0 = *reinterpret_cast<const h16x4*>(H + (size_t)m0.x * 256 + j);
        float w0 = __int_as_float(m0.y);
        acc.x = fmaf((float)h0.x, w0, acc.x); acc.y = fmaf((float)h0.y, w0, acc.y);
        acc.z = fmaf((float)h0.z, w0, acc.z); acc.w = fmaf((float)h0.w, w0, acc.w);
    }
    acc.x += acc2.x; acc.y += acc2.y; acc.z += acc2.z; acc.w += acc2.w;
    *reinterpret_cast<float4*>(P + (size_t)node * 256 + j) = acc;
}

// ---------------- W split+transpose: W[K,256] -> [256,K] bf16 hi/lo ----------------
__global__ __launch_bounds__(256) void k_splitB(const float* __restrict__ W,
                                                unsigned short* __restrict__ Bth,
                                                unsigned short* __restrict__ Btl, int K) {
    int idx = blockIdx.x * 256 + threadIdx.x;
    if (idx >= K * 256) return;
    int k = idx >> 8, nn = idx & 255;
    float v = W[idx];
    unsigned short h = bf16_rne(v);
    float hf = __uint_as_float((unsigned)h << 16);
    unsigned short l = bf16_rne(v - hf);
    Bth[nn * K + k] = h;
    Btl[nn * K + k] = l;
}

// ---------------- split-bf16 MFMA GEMM ----------------
template<bool SPLIT>
__global__ __launch_bounds__(256) void k_gemm_bf16(const unsigned short* __restrict__ Ahg,
                                                   const unsigned short* __restrict__ Alg,
                                                   const unsigned short* __restrict__ Bth,
                                                   const unsigned short* __restrict__ Btl,
                                                   h16* __restrict__ Hh,
                                                   unsigned short* __restrict__ Ph,
                                                   unsigned short* __restrict__ Pl,
                                                   const float* __restrict__ bias,
                                                   int M, int K) {
    __shared__ __attribute__((aligned(16))) char ldsAh[8192];
    __shared__ __attribute__((aligned(16))) char ldsAl[8192];
    __shared__ __attribute__((aligned(16))) char ldsBh[8192];
    __shared__ __attribute__((aligned(16))) char ldsBl[8192];
    const int tid = threadIdx.x;
    const int lane = tid & 63, wid = tid >> 6;
    const int quad = lane >> 4, l16 = lane & 15;
    const int rowBase = blockIdx.x * 128;
    const int colBase = blockIdx.y * 128;
    const int wm = (wid & 1) * 64, wn = (wid >> 1) * 64;

    floatx4 acc[4][4] = {};

    const int c0 = wid * 64 + lane;
    const int c1 = c0 + 256;
    const int r0 = ((c0 >> 6) << 4) + (c0 & 15), q0 = (c0 >> 4) & 3;
    const int r1 = ((c1 >> 6) << 4) + (c1 & 15), q1 = (c1 >> 4) & 3;
    const size_t aoff0 = (size_t)(rowBase + r0) * K + q0 * 8;
    const size_t aoff1 = (size_t)(rowBase + r1) * K + q1 * 8;
    const size_t boff0 = (size_t)(colBase + r0) * K + q0 * 8;
    const size_t boff1 = (size_t)(colBase + r1) * K + q1 * 8;
    const int lo0 = (wid * 64) * 16;
    const int lo1 = (256 + wid * 64) * 16;

    for (int k0 = 0; k0 < K; k0 += 32) {
        load_lds16(ldsAh + lo0, Ahg + aoff0 + k0);
        load_lds16(ldsAh + lo1, Ahg + aoff1 + k0);
        load_lds16(ldsAl + lo0, Alg + aoff0 + k0);
        load_lds16(ldsAl + lo1, Alg + aoff1 + k0);
        load_lds16(ldsBh + lo0, Bth + boff0 + k0);
        load_lds16(ldsBh + lo1, Bth + boff1 + k0);
        load_lds16(ldsBl + lo0, Btl + boff0 + k0);
        load_lds16(ldsBl + lo1, Btl + boff1 + k0);
        __syncthreads();

        const short8* vAh = (const short8*)ldsAh;
        const short8* vAl = (const short8*)ldsAl;
        const short8* vBh = (const short8*)ldsBh;
        const short8* vBl = (const short8*)ldsBl;
        short8 afh[4], afl[4], bfh[4], bfl[4];
#pragma unroll
        for (int mi = 0; mi < 4; ++mi) {
            int idx = ((wm >> 4) + mi) * 64 + quad * 16 + l16;
            afh[mi] = vAh[idx];
            afl[mi] = vAl[idx];
        }
#pragma unroll
        for (int ni = 0; ni < 4; ++ni) {
            int idx = ((wn >> 4) + ni) * 64 + quad * 16 + l16;
            bfh[ni] = vBh[idx];
            bfl[ni] = vBl[idx];
        }
#pragma unroll
        for (int mi = 0; mi < 4; ++mi)
#pragma unroll
            for (int ni = 0; ni < 4; ++ni) {
                acc[mi][ni] = __builtin_amdgcn_mfma_f32_16x16x32_bf16(afh[mi], bfh[ni], acc[mi][ni], 0, 0, 0);
                acc[mi][ni] = __builtin_amdgcn_mfma_f32_16x16x32_bf16(afh[mi], bfl[ni], acc[mi][ni], 0, 0, 0);
                acc[mi][ni] = __builtin_amdgcn_mfma_f32_16x16x32_bf16(afl[mi], bfh[ni], acc[mi][ni], 0, 0, 0);
            }
        __syncthreads();
    }

#pragma unroll
    for (int mi = 0; mi < 4; ++mi) {
#pragma unroll
        for (int r = 0; r < 4; ++r) {
            int grow = rowBase + wm + mi * 16 + quad * 4 + r;
            if (grow < M) {
                if (SPLIT) {
#pragma unroll
                    for (int ni = 0; ni < 4; ++ni) {
                        int gcol = colBase + wn + ni * 16 + l16;
                        float v = acc[mi][ni][r] + bias[gcol];
                        v = fmaxf(v, 0.f);
                        unsigned short h = bf16_rne(v);
                        unsigned short l = bf16_rne(v - __uint_as_float((unsigned)h << 16));
                        Ph[(size_t)grow * 256 + gcol] = h;
                        Pl[(size_t)grow * 256 + gcol] = l;
                    }
                } else {
#pragma unroll
                    for (int ni = 0; ni < 4; ++ni)
                        Hh[(size_t)grow * 256 + colBase + wn + ni * 16 + l16] = (h16)acc[mi][ni][r];
                }
            }
        }
    }
}

// ---------------- FC: out[M,40] = relu(X[M,256]) @ W[256,40] + b ----------------
__global__ __launch_bounds__(256) void k_fc(float* __restrict__ out, const float* __restrict__ X,
                                            const float* __restrict__ W, const float* __restrict__ bias,
                                            int M) {
    __shared__ float Ws[256 * 40];
    __shared__ float Xs[32][68];
    const int tid = threadIdx.x;
#pragma unroll
    for (int t = 0; t < 10; ++t) {
        int idx = (t * 256 + tid) * 4;
        *reinterpret_cast<float4*>(&Ws[idx]) = *reinterpret_cast<const float4*>(W + idx);
    }
    const int rowBase = blockIdx.x * 64;
    const int r  = tid >> 2;
    const int cg = (tid & 3) * 10;
    const int ar = tid >> 3, ac = (tid & 7) << 2;
    float acc[10] = {};

    for (int k0 = 0; k0 < 256; k0 += 32) {
#pragma unroll
        for (int h = 0; h < 2; ++h) {
            int rr = rowBase + ar + h * 32;
            float4 v = make_float4(0.f, 0.f, 0.f, 0.f);
            if (rr < M) v = *reinterpret_cast<const float4*>(X + (size_t)rr * 256 + k0 + ac);
            v.x = fmaxf(v.x, 0.f); v.y = fmaxf(v.y, 0.f);
            v.z = fmaxf(v.z, 0.f); v.w = fmaxf(v.w, 0.f);
            Xs[ac + 0][ar + h * 32] = v.x;
            Xs[ac + 1][ar + h * 32] = v.y;
            Xs[ac + 2][ar + h * 32] = v.z;
            Xs[ac + 3][ar + h * 32] = v.w;
        }
        __syncthreads();
#pragma unroll
        for (int kk = 0; kk < 32; ++kk) {
            float xv = Xs[kk][r];
#pragma unroll
            for (int j = 0; j < 10; ++j)
                acc[j] = fmaf(xv, Ws[(k0 + kk) * 40 + cg + j], acc[j]);
        }
        __syncthreads();
    }

    int orow = rowBase + r;
    if (orow < M) {
#pragma unroll
        for (int j = 0; j < 10; ++j)
            out[(size_t)orow * 40 + cg + j] = acc[j] + bias[cg + j];
    }
}

extern "C" void kernel_launch(void* const* d_in, const int* in_sizes, int n_in,
                              void* d_out, int out_size, void* d_ws, size_t ws_size,
                              hipStream_t stream) {
    const float* x   = (const float*)d_in[0];
    const int*   ei  = (const int*)d_in[1];
    const float* ea  = (const float*)d_in[2];
    const float* W1  = (const float*)d_in[3];
    const float* b1  = (const float*)d_in[4];
    const float* W2  = (const float*)d_in[5];
    const float* b2  = (const float*)d_in[6];
    const float* fcW = (const float*)d_in[7];
    const float* fcb = (const float*)d_in[8];
    float* out = (float*)d_out;

    const int n = NODES, e = EDGES;
    const int* row = ei;
    const int* col = ei + e;

    char* ws = (char*)d_ws;
    char*  Areg   = ws;                                        // 102,400,000 B
    char*  Breg   = ws + 102400000u;                           // 102,400,000 B
    float* dinv   = (float*)(ws + 204800000u);                 // 400,000 B
    unsigned long long* packed = (unsigned long long*)(ws + 205200000u); // 800,000 B
    int*   cnt    = (int*)  (ws + 206000000u);                 // 400,000 B (cursor)
    int*   rowptr = (int*)  (ws + 206400000u);                 // 400,016 B
    int2*  meta   = (int2*) (ws + 206800016u);                 // 12,800,000 B -> 219,600,016
    unsigned short* W1th = (unsigned short*)(ws + 219600016u); // 65,536 B
    unsigned short* W1tl = (unsigned short*)(ws + 219665552u); // 65,536 B
    unsigned short* W2th = (unsigned short*)(ws + 219731088u); // 131,072 B
    unsigned short* W2tl = (unsigned short*)(ws + 219862160u); // 131,072 B -> 219,993,232

    // overlays (time-shared):
    int* partials = (int*)Areg;                                // scan temp (dies before Areg phase 1)
    unsigned short* Xah = (unsigned short*)Areg;               // 25.6 MB (agg(x) hi)   [phase 1]
    unsigned short* Xal = (unsigned short*)(Areg + 25600000u); // 25.6 MB (agg(x) lo)
    h16* x16 = (h16*)(Areg + 51200000u);                       // 25.6 MB (fp16 x)      [phase 1]
    h16* H2h = (h16*)Areg;                                     // 51.2 MB (GEMM2 out)   [phase 2]
    unsigned short* Ph = (unsigned short*)Breg;                // 51.2 MB (relu(P1) hi)
    unsigned short* Pl = (unsigned short*)(Breg + 51200000u);  // 51.2 MB (relu(P1) lo)
    float* P2 = (float*)Breg;                                  // 102.4 MB (gather2 out)[phase 3]

    const int nb = (n + 255) / 256;   // 391
    const int eb = e / 256;           // 6250

    // ---- norm + CSR build ----
    k_init<<<nb, 256, 0, stream>>>(packed, n);
    k_hist<<<eb, 256, 0, stream>>>(packed, col, ea, e);
    k_scan1<<<nb, 256, 0, stream>>>(packed, rowptr, partials, dinv, n);
    k_scan2<<<1, 512, 0, stream>>>(partials, nb);
    k_scan3<<<nb, 256, 0, stream>>>(rowptr, cnt, partials, n);
    k_build<<<eb, 256, 0, stream>>>(cnt, meta, row, col, ea, dinv, e);
    k_splitB<<<128, 256, 0, stream>>>(W1, W1th, W1tl, 128);
    k_splitB<<<256, 256, 0, stream>>>(W2, W2th, W2tl, 256);
    k_half_x<<<(n * 32 + 255) / 256, 256, 0, stream>>>(x, x16, n * 32);

    dim3 gg((n + 127) / 128, 2);

    // layer 1 (agg-first): Xagg = agg(x16) [bf16-split] ; P1relu = relu(Xagg@W1 + b1) [bf16-split]
    k_gather_x<<<(n + 3) / 4, 256, 0, stream>>>(Xah, Xal, x16, dinv, rowptr, meta, n);
    k_gemm_bf16<true><<<gg, 256, 0, stream>>>(Xah, Xal, W1th, W1tl, nullptr, Ph, Pl, b1, n, 128);

    // layer 2: H2 = relu(P1) @ W2 [fp16] ; P2 = agg(H2) + b2 [fp32]
    k_gemm_bf16<false><<<gg, 256, 0, stream>>>(Ph, Pl, W2th, W2tl, H2h, nullptr, nullptr, nullptr, n, 256);
    k_gather<<<(n + 3) / 4, 256, 0, stream>>>(P2, H2h, dinv, rowptr, meta, b2, n);

    // classifier
    k_fc<<<(n + 63) / 64, 256, 0, stream>>>(out, P2, fcW, fcb, n);
}

// Round 8
// 650.578 us; speedup vs baseline: 17.1746x; 1.0776x over previous
//
#include <hip/hip_runtime.h>

#define NODES 100000
#define EDGES 1600000

typedef __attribute__((ext_vector_type(8))) short short8;
typedef __attribute__((ext_vector_type(4))) float floatx4;
typedef _Float16 h16;
typedef __attribute__((ext_vector_type(2))) _Float16 h16x2;
typedef __attribute__((ext_vector_type(4))) _Float16 h16x4;
typedef __attribute__((ext_vector_type(8))) _Float16 h16x8;

__device__ inline unsigned short bf16_rne(float x) {
    unsigned u = __float_as_uint(x);
    u += 0x7FFF + ((u >> 16) & 1);
    return (unsigned short)(u >> 16);
}

__device__ inline void load_lds16(void* lds, const void* g) {
    __builtin_amdgcn_global_load_lds((const __attribute__((address_space(1))) void*)g,
                                     (__attribute__((address_space(3))) void*)lds, 16, 0, 0);
}

// ---------------- fused prep: W1 split, W2 split, packed init, x->fp16 ----------------
// blocks: [0,128) W1 | [128,384) W2 | [384,775) init | [775,13275) half_x
__global__ __launch_bounds__(256) void k_prep(const float* __restrict__ W1,
                                              unsigned short* __restrict__ W1th, unsigned short* __restrict__ W1tl,
                                              const float* __restrict__ W2,
                                              unsigned short* __restrict__ W2th, unsigned short* __restrict__ W2tl,
                                              const float* __restrict__ x, h16* __restrict__ x16,
                                              unsigned long long* __restrict__ packed, int n) {
    int b = blockIdx.x;
    if (b < 384) {
        const float* W = (b < 128) ? W1 : W2;
        unsigned short* Bth = (b < 128) ? W1th : W2th;
        unsigned short* Btl = (b < 128) ? W1tl : W2tl;
        int K = (b < 128) ? 128 : 256;
        int idx = ((b < 128) ? b : (b - 128)) * 256 + threadIdx.x;
        if (idx < K * 256) {
            int k = idx >> 8, nn = idx & 255;
            float v = W[idx];
            unsigned short h = bf16_rne(v);
            unsigned short l = bf16_rne(v - __uint_as_float((unsigned)h << 16));
            Bth[nn * K + k] = h;
            Btl[nn * K + k] = l;
        }
    } else if (b < 775) {
        int i = (b - 384) * 256 + threadIdx.x;
        if (i < n) packed[i] = 0ull;
    } else {
        int i = (b - 775) * 256 + threadIdx.x;   // over n*32 float4 groups
        if (i < n * 32) {
            float4 v = reinterpret_cast<const float4*>(x)[i];
            h16x4 h;
            h.x = (h16)v.x; h.y = (h16)v.y; h.z = (h16)v.z; h.w = (h16)v.w;
            reinterpret_cast<h16x4*>(x16)[i] = h;
        }
    }
}

// ---------------- packed histogram + rank: atomic return gives in-bucket rank ----------------
__global__ __launch_bounds__(256) void k_hist(unsigned long long* __restrict__ packed,
                                              unsigned short* __restrict__ rank,
                                              const int* __restrict__ col,
                                              const float* __restrict__ ew, int e) {
    int i = blockIdx.x * 256 + threadIdx.x;
    if (i < e) {
        int c = col[i];
        unsigned long long v = (1ull << 40) |
            (unsigned long long)__float2uint_rn(ew[i] * 1048576.0f);
        unsigned long long old = atomicAdd(&packed[c], v);
        rank[i] = (unsigned short)(old >> 40);   // count before this edge (max degree << 65536)
    }
}

// ---------------- scan phase 1: unpack cnt, compute dinv, block-scan ----------------
__global__ __launch_bounds__(256) void k_scan1(const unsigned long long* __restrict__ packed,
                                               int* __restrict__ rowptr,
                                               int* __restrict__ partials,
                                               float* __restrict__ dinv, int n) {
    __shared__ int wtot[4];
    const int tid = threadIdx.x, lane = tid & 63, wid = tid >> 6;
    int i = blockIdx.x * 256 + tid;
    int v = 0;
    if (i < n) {
        unsigned long long p = packed[i];
        v = (int)(p >> 40);
        float deg = 1.0f + (float)(p & 0xFFFFFFFFFFull) * (1.0f / 1048576.0f);
        dinv[i] = rsqrtf(deg);
    }
    int incl = v;
#pragma unroll
    for (int off = 1; off < 64; off <<= 1) {
        int t = __shfl_up(incl, off, 64);
        if (lane >= off) incl += t;
    }
    if (lane == 63) wtot[wid] = incl;
    __syncthreads();
    int woff = 0;
    for (int k = 0; k < wid; ++k) woff += wtot[k];
    if (i < n) rowptr[i] = woff + incl - v;
    if (tid == 255) partials[blockIdx.x] = woff + incl;
}

__global__ __launch_bounds__(512) void k_scan2(int* __restrict__ partials, int nb) {
    __shared__ int wtot[8];
    const int tid = threadIdx.x, lane = tid & 63, wid = tid >> 6;
    int v = (tid < nb) ? partials[tid] : 0;
    int incl = v;
#pragma unroll
    for (int off = 1; off < 64; off <<= 1) {
        int t = __shfl_up(incl, off, 64);
        if (lane >= off) incl += t;
    }
    if (lane == 63) wtot[wid] = incl;
    __syncthreads();
    int woff = 0;
    for (int k = 0; k < wid; ++k) woff += wtot[k];
    if (tid < nb) partials[tid] = woff + incl - v;
}

__global__ __launch_bounds__(256) void k_scan3(int* __restrict__ rowptr,
                                               const int* __restrict__ partials, int n) {
    int i = blockIdx.x * 256 + threadIdx.x;
    if (i < n) rowptr[i] += partials[blockIdx.x];
    if (blockIdx.x == 0 && threadIdx.x == 0) rowptr[n] = EDGES;
}

// ---------------- CSR build: atomic-free via precomputed rank ----------------
__global__ __launch_bounds__(256) void k_build(const int* __restrict__ rowptr,
                                               const unsigned short* __restrict__ rank,
                                               int2* __restrict__ meta,
                                               const int* __restrict__ row, const int* __restrict__ col,
                                               const float* __restrict__ ew,
                                               const float* __restrict__ dinv, int e) {
    int i = blockIdx.x * 256 + threadIdx.x;
    if (i >= e) return;
    int r = row[i], c = col[i];
    float w = dinv[r] * ew[i] * dinv[c];
    int pos = rowptr[c] + rank[i];
    meta[pos] = make_int2(r, __float_as_int(w));
}

// ---------------- gather on fp16 x (128 ch): Xagg = agg(x), epilogue bf16 split ----------------
__global__ __launch_bounds__(256) void k_gather_x(unsigned short* __restrict__ Xh,
                                                  unsigned short* __restrict__ Xl,
                                                  const h16* __restrict__ x16,
                                                  const float* __restrict__ dinv,
                                                  const int* __restrict__ rowptr,
                                                  const int2* __restrict__ meta, int n) {
    int node = (blockIdx.x << 2) + (threadIdx.x >> 6);
    if (node >= n) return;
    const int lane = threadIdx.x & 63;
    const int j = lane << 1;
    float di = dinv[node];
    float s = di * di;
    h16x2 xs = *reinterpret_cast<const h16x2*>(x16 + (size_t)node * 128 + j);
    float2 a0 = make_float2((float)xs.x * s, (float)xs.y * s);
    float2 a1 = make_float2(0.f, 0.f);

    int p = rowptr[node];
    const int end = rowptr[node + 1];
    for (; p + 3 < end; p += 4) {
        int2 m0 = meta[p],     m1 = meta[p + 1];
        int2 m2 = meta[p + 2], m3 = meta[p + 3];
        h16x2 h0 = *reinterpret_cast<const h16x2*>(x16 + (size_t)m0.x * 128 + j);
        h16x2 h1 = *reinterpret_cast<const h16x2*>(x16 + (size_t)m1.x * 128 + j);
        h16x2 h2 = *reinterpret_cast<const h16x2*>(x16 + (size_t)m2.x * 128 + j);
        h16x2 h3 = *reinterpret_cast<const h16x2*>(x16 + (size_t)m3.x * 128 + j);
        float w0 = __int_as_float(m0.y), w1 = __int_as_float(m1.y);
        float w2 = __int_as_float(m2.y), w3 = __int_as_float(m3.y);
        a0.x = fmaf((float)h0.x, w0, a0.x); a0.y = fmaf((float)h0.y, w0, a0.y);
        a1.x = fmaf((float)h1.x, w1, a1.x); a1.y = fmaf((float)h1.y, w1, a1.y);
        a0.x = fmaf((float)h2.x, w2, a0.x); a0.y = fmaf((float)h2.y, w2, a0.y);
        a1.x = fmaf((float)h3.x, w3, a1.x); a1.y = fmaf((float)h3.y, w3, a1.y);
    }
    for (; p < end; ++p) {
        int2 m0 = meta[p];
        h16x2 h0 = *reinterpret_cast<const h16x2*>(x16 + (size_t)m0.x * 128 + j);
        float w0 = __int_as_float(m0.y);
        a0.x = fmaf((float)h0.x, w0, a0.x); a0.y = fmaf((float)h0.y, w0, a0.y);
    }
    a0.x += a1.x; a0.y += a1.y;

    ushort2 hh, ll;
    hh.x = bf16_rne(a0.x); ll.x = bf16_rne(a0.x - __uint_as_float((unsigned)hh.x << 16));
    hh.y = bf16_rne(a0.y); ll.y = bf16_rne(a0.y - __uint_as_float((unsigned)hh.y << 16));
    *reinterpret_cast<ushort2*>(Xh + (size_t)node * 128 + j) = hh;
    *reinterpret_cast<ushort2*>(Xl + (size_t)node * 128 + j) = ll;
}

// ---------------- gather-reduce on fp16 H2 (256 ch, + bias, relu) -> fp16 P2 ----------------
__global__ __launch_bounds__(256) void k_gather(h16* __restrict__ P,
                                                const h16* __restrict__ H,
                                                const float* __restrict__ dinv,
                                                const int* __restrict__ rowptr,
                                                const int2* __restrict__ meta,
                                                const float* __restrict__ bias, int n) {
    int node = (blockIdx.x << 2) + (threadIdx.x >> 6);
    if (node >= n) return;
    const int lane = threadIdx.x & 63;
    const int j = lane << 2;
    float di = dinv[node];
    float s = di * di;
    float4 b = *reinterpret_cast<const float4*>(bias + j);
    h16x4 hv = *reinterpret_cast<const h16x4*>(H + (size_t)node * 256 + j);
    float4 acc;
    acc.x = fmaf((float)hv.x, s, b.x); acc.y = fmaf((float)hv.y, s, b.y);
    acc.z = fmaf((float)hv.z, s, b.z); acc.w = fmaf((float)hv.w, s, b.w);
    float4 acc2 = make_float4(0.f, 0.f, 0.f, 0.f);

    int p = rowptr[node];
    const int end = rowptr[node + 1];
    for (; p + 3 < end; p += 4) {
        int2 m0 = meta[p],     m1 = meta[p + 1];
        int2 m2 = meta[p + 2], m3 = meta[p + 3];
        h16x4 h0 = *reinterpret_cast<const h16x4*>(H + (size_t)m0.x * 256 + j);
        h16x4 h1 = *reinterpret_cast<const h16x4*>(H + (size_t)m1.x * 256 + j);
        h16x4 h2 = *reinterpret_cast<const h16x4*>(H + (size_t)m2.x * 256 + j);
        h16x4 h3 = *reinterpret_cast<const h16x4*>(H + (size_t)m3.x * 256 + j);
        float w0 = __int_as_float(m0.y), w1 = __int_as_float(m1.y);
        float w2 = __int_as_float(m2.y), w3 = __int_as_float(m3.y);
        acc.x  = fmaf((float)h0.x, w0, acc.x);  acc.y  = fmaf((float)h0.y, w0, acc.y);
        acc.z  = fmaf((float)h0.z, w0, acc.z);  acc.w  = fmaf((float)h0.w, w0, acc.w);
        acc2.x = fmaf((float)h1.x, w1, acc2.x); acc2.y = fmaf((float)h1.y, w1, acc2.y);
        acc2.z = fmaf((float)h1.z, w1, acc2.z); acc2.w = fmaf((float)h1.w, w1, acc2.w);
        acc.x  = fmaf((float)h2.x, w2, acc.x);  acc.y  = fmaf((float)h2.y, w2, acc.y);
        acc.z  = fmaf((float)h2.z, w2, acc.z);  acc.w  = fmaf((float)h2.w, w2, acc.w);
        acc2.x = fmaf((float)h3.x, w3, acc2.x); acc2.y = fmaf((float)h3.y, w3, acc2.y);
        acc2.z = fmaf((float)h3.z, w3, acc2.z); acc2.w = fmaf((float)h3.w, w3, acc2.w);
    }
    for (; p < end; ++p) {
        int2 m0 = meta[p];
        h16x4 h0 = *reinterpret_cast<const h16x4*>(H + (size_t)m0.x * 256 + j);
        float w0 = __int_as_float(m0.y);
        acc.x = fmaf((float)h0.x, w0, acc.x); acc.y = fmaf((float)h0.y, w0, acc.y);
        acc.z = fmaf((float)h0.z, w0, acc.z); acc.w = fmaf((float)h0.w, w0, acc.w);
    }
    acc.x += acc2.x; acc.y += acc2.y; acc.z += acc2.z; acc.w += acc2.w;

    h16x4 o;   // fused relu + fp16 store (feeds FC)
    o.x = (h16)fmaxf(acc.x, 0.f); o.y = (h16)fmaxf(acc.y, 0.f);
    o.z = (h16)fmaxf(acc.z, 0.f); o.w = (h16)fmaxf(acc.w, 0.f);
    *reinterpret_cast<h16x4*>(P + (size_t)node * 256 + j) = o;
}

// ---------------- split-bf16 MFMA GEMM ----------------
template<bool SPLIT>
__global__ __launch_bounds__(256) void k_gemm_bf16(const unsigned short* __restrict__ Ahg,
                                                   const unsigned short* __restrict__ Alg,
                                                   const unsigned short* __restrict__ Bth,
                                                   const unsigned short* __restrict__ Btl,
                                                   h16* __restrict__ Hh,
                                                   unsigned short* __restrict__ Ph,
                                                   unsigned short* __restrict__ Pl,
                                                   const float* __restrict__ bias,
                                                   int M, int K) {
    __shared__ __attribute__((aligned(16))) char ldsAh[8192];
    __shared__ __attribute__((aligned(16))) char ldsAl[8192];
    __shared__ __attribute__((aligned(16))) char ldsBh[8192];
    __shared__ __attribute__((aligned(16))) char ldsBl[8192];
    const int tid = threadIdx.x;
    const int lane = tid & 63, wid = tid >> 6;
    const int quad = lane >> 4, l16 = lane & 15;
    const int rowBase = blockIdx.x * 128;
    const int colBase = blockIdx.y * 128;
    const int wm = (wid & 1) * 64, wn = (wid >> 1) * 64;

    floatx4 acc[4][4] = {};

    const int c0 = wid * 64 + lane;
    const int c1 = c0 + 256;
    const int r0 = ((c0 >> 6) << 4) + (c0 & 15), q0 = (c0 >> 4) & 3;
    const int r1 = ((c1 >> 6) << 4) + (c1 & 15), q1 = (c1 >> 4) & 3;
    const size_t aoff0 = (size_t)(rowBase + r0) * K + q0 * 8;
    const size_t aoff1 = (size_t)(rowBase + r1) * K + q1 * 8;
    const size_t boff0 = (size_t)(colBase + r0) * K + q0 * 8;
    const size_t boff1 = (size_t)(colBase + r1) * K + q1 * 8;
    const int lo0 = (wid * 64) * 16;
    const int lo1 = (256 + wid * 64) * 16;

    for (int k0 = 0; k0 < K; k0 += 32) {
        load_lds16(ldsAh + lo0, Ahg + aoff0 + k0);
        load_lds16(ldsAh + lo1, Ahg + aoff1 + k0);
        load_lds16(ldsAl + lo0, Alg + aoff0 + k0);
        load_lds16(ldsAl + lo1, Alg + aoff1 + k0);
        load_lds16(ldsBh + lo0, Bth + boff0 + k0);
        load_lds16(ldsBh + lo1, Bth + boff1 + k0);
        load_lds16(ldsBl + lo0, Btl + boff0 + k0);
        load_lds16(ldsBl + lo1, Btl + boff1 + k0);
        __syncthreads();

        const short8* vAh = (const short8*)ldsAh;
        const short8* vAl = (const short8*)ldsAl;
        const short8* vBh = (const short8*)ldsBh;
        const short8* vBl = (const short8*)ldsBl;
        short8 afh[4], afl[4], bfh[4], bfl[4];
#pragma unroll
        for (int mi = 0; mi < 4; ++mi) {
            int idx = ((wm >> 4) + mi) * 64 + quad * 16 + l16;
            afh[mi] = vAh[idx];
            afl[mi] = vAl[idx];
        }
#pragma unroll
        for (int ni = 0; ni < 4; ++ni) {
            int idx = ((wn >> 4) + ni) * 64 + quad * 16 + l16;
            bfh[ni] = vBh[idx];
            bfl[ni] = vBl[idx];
        }
#pragma unroll
        for (int mi = 0; mi < 4; ++mi)
#pragma unroll
            for (int ni = 0; ni < 4; ++ni) {
                acc[mi][ni] = __builtin_amdgcn_mfma_f32_16x16x32_bf16(afh[mi], bfh[ni], acc[mi][ni], 0, 0, 0);
                acc[mi][ni] = __builtin_amdgcn_mfma_f32_16x16x32_bf16(afh[mi], bfl[ni], acc[mi][ni], 0, 0, 0);
                acc[mi][ni] = __builtin_amdgcn_mfma_f32_16x16x32_bf16(afl[mi], bfh[ni], acc[mi][ni], 0, 0, 0);
            }
        __syncthreads();
    }

#pragma unroll
    for (int mi = 0; mi < 4; ++mi) {
#pragma unroll
        for (int r = 0; r < 4; ++r) {
            int grow = rowBase + wm + mi * 16 + quad * 4 + r;
            if (grow < M) {
                if (SPLIT) {
#pragma unroll
                    for (int ni = 0; ni < 4; ++ni) {
                        int gcol = colBase + wn + ni * 16 + l16;
                        float v = acc[mi][ni][r] + bias[gcol];
                        v = fmaxf(v, 0.f);
                        unsigned short h = bf16_rne(v);
                        unsigned short l = bf16_rne(v - __uint_as_float((unsigned)h << 16));
                        Ph[(size_t)grow * 256 + gcol] = h;
                        Pl[(size_t)grow * 256 + gcol] = l;
                    }
                } else {
#pragma unroll
                    for (int ni = 0; ni < 4; ++ni)
                        Hh[(size_t)grow * 256 + colBase + wn + ni * 16 + l16] = (h16)acc[mi][ni][r];
                }
            }
        }
    }
}

// ---------------- FC: out[M,40] = X16[M,256] @ W[256,40] + b  (X16 already relu'd fp16) ----------------
__global__ __launch_bounds__(256) void k_fc(float* __restrict__ out, const h16* __restrict__ X,
                                            const float* __restrict__ W, const float* __restrict__ bias,
                                            int M) {
    __shared__ float Ws[256 * 40];
    __shared__ float Xs[32][69];
    const int tid = threadIdx.x;
#pragma unroll
    for (int t = 0; t < 10; ++t) {
        int idx = (t * 256 + tid) * 4;
        *reinterpret_cast<float4*>(&Ws[idx]) = *reinterpret_cast<const float4*>(W + idx);
    }
    const int rowBase = blockIdx.x * 64;
    const int r  = tid >> 2;          // 0..63 (also staging row)
    const int cg = (tid & 3) * 10;
    const int kq = (tid & 3) << 3;    // staging k-offset: 0,8,16,24
    float acc[10] = {};

    for (int k0 = 0; k0 < 256; k0 += 32) {
        int rr = rowBase + r;
        h16x8 v = {};
        if (rr < M) v = *reinterpret_cast<const h16x8*>(X + (size_t)rr * 256 + k0 + kq);
#pragma unroll
        for (int j = 0; j < 8; ++j) Xs[kq + j][r] = (float)v[j];
        __syncthreads();
#pragma unroll
        for (int kk = 0; kk < 32; ++kk) {
            float xv = Xs[kk][r];
#pragma unroll
            for (int j = 0; j < 10; ++j)
                acc[j] = fmaf(xv, Ws[(k0 + kk) * 40 + cg + j], acc[j]);
        }
        __syncthreads();
    }

    int orow = rowBase + r;
    if (orow < M) {
#pragma unroll
        for (int j = 0; j < 10; ++j)
            out[(size_t)orow * 40 + cg + j] = acc[j] + bias[cg + j];
    }
}

extern "C" void kernel_launch(void* const* d_in, const int* in_sizes, int n_in,
                              void* d_out, int out_size, void* d_ws, size_t ws_size,
                              hipStream_t stream) {
    const float* x   = (const float*)d_in[0];
    const int*   ei  = (const int*)d_in[1];
    const float* ea  = (const float*)d_in[2];
    const float* W1  = (const float*)d_in[3];
    const float* b1  = (const float*)d_in[4];
    const float* W2  = (const float*)d_in[5];
    const float* b2  = (const float*)d_in[6];
    const float* fcW = (const float*)d_in[7];
    const float* fcb = (const float*)d_in[8];
    float* out = (float*)d_out;

    const int n = NODES, e = EDGES;
    const int* row = ei;
    const int* col = ei + e;

    char* ws = (char*)d_ws;
    char*  Areg   = ws;                                        // 102,400,000 B
    char*  Breg   = ws + 102400000u;                           // 102,400,000 B
    float* dinv   = (float*)(ws + 204800000u);                 // 400,000 B
    unsigned long long* packed = (unsigned long long*)(ws + 205200000u); // 800,000 B
    int*   rowptr = (int*)  (ws + 206000000u);                 // 400,016 B -> 206,400,016
    int2*  meta   = (int2*) (ws + 206400016u);                 // 12,800,000 B -> 219,200,016
    unsigned short* W1th = (unsigned short*)(ws + 219200016u); // 65,536 B
    unsigned short* W1tl = (unsigned short*)(ws + 219265552u); // 65,536 B
    unsigned short* W2th = (unsigned short*)(ws + 219331088u); // 131,072 B
    unsigned short* W2tl = (unsigned short*)(ws + 219462160u); // 131,072 B -> 219,593,232

    // overlays (time-shared):
    int* partials = (int*)Areg;                                // scan temp (dies before gather_x)
    unsigned short* Xah = (unsigned short*)Areg;               // 25.6 MB (agg(x) hi)   [phase 1]
    unsigned short* Xal = (unsigned short*)(Areg + 25600000u); // 25.6 MB (agg(x) lo)
    h16* x16 = (h16*)(Areg + 51200000u);                       // 25.6 MB (fp16 x)      [phase 1]
    h16* H2h = (h16*)Areg;                                     // 51.2 MB (GEMM2 out)   [phase 2]
    unsigned short* rank = (unsigned short*)Breg;              // 3.2 MB (hist->build; dies before GEMM1)
    unsigned short* Ph = (unsigned short*)Breg;                // 51.2 MB (relu(P1) hi)
    unsigned short* Pl = (unsigned short*)(Breg + 51200000u);  // 51.2 MB (relu(P1) lo)
    h16* P2h = (h16*)Breg;                                     // 51.2 MB (relu gather2 out) [phase 3]

    const int nb = (n + 255) / 256;   // 391
    const int eb = e / 256;           // 6250

    // ---- prep (W splits + packed init + x->fp16), then CSR build ----
    k_prep<<<13275, 256, 0, stream>>>(W1, W1th, W1tl, W2, W2th, W2tl, x, x16, packed, n);
    k_hist<<<eb, 256, 0, stream>>>(packed, rank, col, ea, e);
    k_scan1<<<nb, 256, 0, stream>>>(packed, rowptr, partials, dinv, n);
    k_scan2<<<1, 512, 0, stream>>>(partials, nb);
    k_scan3<<<nb, 256, 0, stream>>>(rowptr, partials, n);
    k_build<<<eb, 256, 0, stream>>>(rowptr, rank, meta, row, col, ea, dinv, e);

    dim3 gg((n + 127) / 128, 2);

    // layer 1 (agg-first): Xagg = agg(x16) [bf16-split] ; P1relu = relu(Xagg@W1 + b1) [bf16-split]
    k_gather_x<<<(n + 3) / 4, 256, 0, stream>>>(Xah, Xal, x16, dinv, rowptr, meta, n);
    k_gemm_bf16<true><<<gg, 256, 0, stream>>>(Xah, Xal, W1th, W1tl, nullptr, Ph, Pl, b1, n, 128);

    // layer 2: H2 = relu(P1) @ W2 [fp16] ; P2 = relu(agg(H2) + b2) [fp16]
    k_gemm_bf16<false><<<gg, 256, 0, stream>>>(Ph, Pl, W2th, W2tl, H2h, nullptr, nullptr, nullptr, n, 256);
    k_gather<<<(n + 3) / 4, 256, 0, stream>>>(P2h, H2h, dinv, rowptr, meta, b2, n);

    // classifier
    k_fc<<<(n + 63) / 64, 256, 0, stream>>>(out, P2h, fcW, fcb, n);
}

// Round 9
// 614.489 us; speedup vs baseline: 18.1833x; 1.0587x over previous
//
#include <hip/hip_runtime.h>

#define NODES 100000
#define EDGES 1600000

typedef __attribute__((ext_vector_type(4))) float floatx4;
typedef _Float16 h16;
typedef __attribute__((ext_vector_type(2))) _Float16 h16x2;
typedef __attribute__((ext_vector_type(4))) _Float16 h16x4;
typedef __attribute__((ext_vector_type(8))) _Float16 h16x8;
typedef __attribute__((ext_vector_type(8))) _Float16 half8;

#define WSCALE 64.0f
#define WINV   (1.0f / 64.0f)

__device__ inline void load_lds16(void* lds, const void* g) {
    __builtin_amdgcn_global_load_lds((const __attribute__((address_space(1))) void*)g,
                                     (__attribute__((address_space(3))) void*)lds, 16, 0, 0);
}

// ---------------- init packed accumulator ----------------
__global__ __launch_bounds__(256) void k_init(unsigned long long* __restrict__ packed, int n) {
    int i = blockIdx.x * 256 + threadIdx.x;
    if (i < n) packed[i] = 0ull;
}

// ---------------- fused: histogram+rank | W1 split | W2 split | x->fp16 ----------------
// blocks [0,6250): hist | [6250,6378): W1 | [6378,6634): W2 | [6634,19134): x16
__device__ inline void w_split(const float* W, h16* Wh, h16* Wl, int idx, int K) {
    int k = idx >> 8, nn = idx & 255;
    float v = W[idx] * WSCALE;
    h16 h = (h16)v;
    h16 l = (h16)(v - (float)h);
    Wh[nn * K + k] = h;
    Wl[nn * K + k] = l;
}

__global__ __launch_bounds__(256) void k_hist(unsigned long long* __restrict__ packed,
                                              unsigned short* __restrict__ rank,
                                              const int* __restrict__ col,
                                              const float* __restrict__ ew, int e,
                                              const float* __restrict__ W1, h16* __restrict__ W1h, h16* __restrict__ W1l,
                                              const float* __restrict__ W2, h16* __restrict__ W2h, h16* __restrict__ W2l,
                                              const float* __restrict__ x, h16* __restrict__ x16, int n) {
    int b = blockIdx.x;
    if (b < 6250) {
        int i = b * 256 + threadIdx.x;
        if (i < e) {
            int c = col[i];
            unsigned long long v = (1ull << 40) |
                (unsigned long long)__float2uint_rn(ew[i] * 1048576.0f);
            unsigned long long old = atomicAdd(&packed[c], v);
            rank[i] = (unsigned short)(old >> 40);
        }
    } else if (b < 6378) {
        w_split(W1, W1h, W1l, (b - 6250) * 256 + threadIdx.x, 128);
    } else if (b < 6634) {
        w_split(W2, W2h, W2l, (b - 6378) * 256 + threadIdx.x, 256);
    } else {
        int i = (b - 6634) * 256 + threadIdx.x;
        if (i < n * 32) {
            float4 v = reinterpret_cast<const float4*>(x)[i];
            h16x4 h;
            h.x = (h16)v.x; h.y = (h16)v.y; h.z = (h16)v.z; h.w = (h16)v.w;
            reinterpret_cast<h16x4*>(x16)[i] = h;
        }
    }
}

// ---------------- scan phase 1: unpack cnt, compute dinv, block-scan ----------------
__global__ __launch_bounds__(256) void k_scan1(const unsigned long long* __restrict__ packed,
                                               int* __restrict__ rowptr,
                                               int* __restrict__ partials,
                                               float* __restrict__ dinv, int n) {
    __shared__ int wtot[4];
    const int tid = threadIdx.x, lane = tid & 63, wid = tid >> 6;
    int i = blockIdx.x * 256 + tid;
    int v = 0;
    if (i < n) {
        unsigned long long p = packed[i];
        v = (int)(p >> 40);
        float deg = 1.0f + (float)(p & 0xFFFFFFFFFFull) * (1.0f / 1048576.0f);
        dinv[i] = rsqrtf(deg);
    }
    int incl = v;
#pragma unroll
    for (int off = 1; off < 64; off <<= 1) {
        int t = __shfl_up(incl, off, 64);
        if (lane >= off) incl += t;
    }
    if (lane == 63) wtot[wid] = incl;
    __syncthreads();
    int woff = 0;
    for (int k = 0; k < wid; ++k) woff += wtot[k];
    if (i < n) rowptr[i] = woff + incl - v;
    if (tid == 255) partials[blockIdx.x] = woff + incl;
}

__global__ __launch_bounds__(512) void k_scan2(int* __restrict__ partials, int nb) {
    __shared__ int wtot[8];
    const int tid = threadIdx.x, lane = tid & 63, wid = tid >> 6;
    int v = (tid < nb) ? partials[tid] : 0;
    int incl = v;
#pragma unroll
    for (int off = 1; off < 64; off <<= 1) {
        int t = __shfl_up(incl, off, 64);
        if (lane >= off) incl += t;
    }
    if (lane == 63) wtot[wid] = incl;
    __syncthreads();
    int woff = 0;
    for (int k = 0; k < wid; ++k) woff += wtot[k];
    if (tid < nb) partials[tid] = woff + incl - v;
}

__global__ __launch_bounds__(256) void k_scan3(int* __restrict__ rowptr,
                                               const int* __restrict__ partials, int n) {
    int i = blockIdx.x * 256 + threadIdx.x;
    if (i < n) rowptr[i] += partials[blockIdx.x];
    if (blockIdx.x == 0 && threadIdx.x == 0) rowptr[n] = EDGES;
}

// ---------------- CSR build: atomic-free via precomputed rank ----------------
__global__ __launch_bounds__(256) void k_build(const int* __restrict__ rowptr,
                                               const unsigned short* __restrict__ rank,
                                               int2* __restrict__ meta,
                                               const int* __restrict__ row, const int* __restrict__ col,
                                               const float* __restrict__ ew,
                                               const float* __restrict__ dinv, int e) {
    int i = blockIdx.x * 256 + threadIdx.x;
    if (i >= e) return;
    int r = row[i], c = col[i];
    float w = dinv[r] * ew[i] * dinv[c];
    int pos = rowptr[c] + rank[i];
    meta[pos] = make_int2(r, __float_as_int(w));
}

// ---------------- gather on fp16 x (128 ch): Xagg = agg(x16), fp16 out ----------------
__global__ __launch_bounds__(256) void k_gather_x(h16* __restrict__ Xa,
                                                  const h16* __restrict__ x16,
                                                  const float* __restrict__ dinv,
                                                  const int* __restrict__ rowptr,
                                                  const int2* __restrict__ meta, int n) {
    int node = (blockIdx.x << 2) + (threadIdx.x >> 6);
    if (node >= n) return;
    const int lane = threadIdx.x & 63;
    const int j = lane << 1;
    float di = dinv[node];
    float s = di * di;
    h16x2 xs = *reinterpret_cast<const h16x2*>(x16 + (size_t)node * 128 + j);
    float2 a0 = make_float2((float)xs.x * s, (float)xs.y * s);
    float2 a1 = make_float2(0.f, 0.f);

    int p = rowptr[node];
    const int end = rowptr[node + 1];
    for (; p + 3 < end; p += 4) {
        int2 m0 = meta[p],     m1 = meta[p + 1];
        int2 m2 = meta[p + 2], m3 = meta[p + 3];
        h16x2 h0 = *reinterpret_cast<const h16x2*>(x16 + (size_t)m0.x * 128 + j);
        h16x2 h1 = *reinterpret_cast<const h16x2*>(x16 + (size_t)m1.x * 128 + j);
        h16x2 h2 = *reinterpret_cast<const h16x2*>(x16 + (size_t)m2.x * 128 + j);
        h16x2 h3 = *reinterpret_cast<const h16x2*>(x16 + (size_t)m3.x * 128 + j);
        float w0 = __int_as_float(m0.y), w1 = __int_as_float(m1.y);
        float w2 = __int_as_float(m2.y), w3 = __int_as_float(m3.y);
        a0.x = fmaf((float)h0.x, w0, a0.x); a0.y = fmaf((float)h0.y, w0, a0.y);
        a1.x = fmaf((float)h1.x, w1, a1.x); a1.y = fmaf((float)h1.y, w1, a1.y);
        a0.x = fmaf((float)h2.x, w2, a0.x); a0.y = fmaf((float)h2.y, w2, a0.y);
        a1.x = fmaf((float)h3.x, w3, a1.x); a1.y = fmaf((float)h3.y, w3, a1.y);
    }
    for (; p < end; ++p) {
        int2 m0 = meta[p];
        h16x2 h0 = *reinterpret_cast<const h16x2*>(x16 + (size_t)m0.x * 128 + j);
        float w0 = __int_as_float(m0.y);
        a0.x = fmaf((float)h0.x, w0, a0.x); a0.y = fmaf((float)h0.y, w0, a0.y);
    }
    a0.x += a1.x; a0.y += a1.y;

    h16x2 o;
    o.x = (h16)a0.x; o.y = (h16)a0.y;
    *reinterpret_cast<h16x2*>(Xa + (size_t)node * 128 + j) = o;
}

// ---------------- gather-reduce on fp16 H2 (256 ch, + bias, relu) -> fp16 P2 ----------------
__global__ __launch_bounds__(256) void k_gather(h16* __restrict__ P,
                                                const h16* __restrict__ H,
                                                const float* __restrict__ dinv,
                                                const int* __restrict__ rowptr,
                                                const int2* __restrict__ meta,
                                                const float* __restrict__ bias, int n) {
    int node = (blockIdx.x << 2) + (threadIdx.x >> 6);
    if (node >= n) return;
    const int lane = threadIdx.x & 63;
    const int j = lane << 2;
    float di = dinv[node];
    float s = di * di;
    float4 b = *reinterpret_cast<const float4*>(bias + j);
    h16x4 hv = *reinterpret_cast<const h16x4*>(H + (size_t)node * 256 + j);
    float4 acc;
    acc.x = fmaf((float)hv.x, s, b.x); acc.y = fmaf((float)hv.y, s, b.y);
    acc.z = fmaf((float)hv.z, s, b.z); acc.w = fmaf((float)hv.w, s, b.w);
    float4 acc2 = make_float4(0.f, 0.f, 0.f, 0.f);

    int p = rowptr[node];
    const int end = rowptr[node + 1];
    for (; p + 3 < end; p += 4) {
        int2 m0 = meta[p],     m1 = meta[p + 1];
        int2 m2 = meta[p + 2], m3 = meta[p + 3];
        h16x4 h0 = *reinterpret_cast<const h16x4*>(H + (size_t)m0.x * 256 + j);
        h16x4 h1 = *reinterpret_cast<const h16x4*>(H + (size_t)m1.x * 256 + j);
        h16x4 h2 = *reinterpret_cast<const h16x4*>(H + (size_t)m2.x * 256 + j);
        h16x4 h3 = *reinterpret_cast<const h16x4*>(H + (size_t)m3.x * 256 + j);
        float w0 = __int_as_float(m0.y), w1 = __int_as_float(m1.y);
        float w2 = __int_as_float(m2.y), w3 = __int_as_float(m3.y);
        acc.x  = fmaf((float)h0.x, w0, acc.x);  acc.y  = fmaf((float)h0.y, w0, acc.y);
        acc.z  = fmaf((float)h0.z, w0, acc.z);  acc.w  = fmaf((float)h0.w, w0, acc.w);
        acc2.x = fmaf((float)h1.x, w1, acc2.x); acc2.y = fmaf((float)h1.y, w1, acc2.y);
        acc2.z = fmaf((float)h1.z, w1, acc2.z); acc2.w = fmaf((float)h1.w, w1, acc2.w);
        acc.x  = fmaf((float)h2.x, w2, acc.x);  acc.y  = fmaf((float)h2.y, w2, acc.y);
        acc.z  = fmaf((float)h2.z, w2, acc.z);  acc.w  = fmaf((float)h2.w, w2, acc.w);
        acc2.x = fmaf((float)h3.x, w3, acc2.x); acc2.y = fmaf((float)h3.y, w3, acc2.y);
        acc2.z = fmaf((float)h3.z, w3, acc2.z); acc2.w = fmaf((float)h3.w, w3, acc2.w);
    }
    for (; p < end; ++p) {
        int2 m0 = meta[p];
        h16x4 h0 = *reinterpret_cast<const h16x4*>(H + (size_t)m0.x * 256 + j);
        float w0 = __int_as_float(m0.y);
        acc.x = fmaf((float)h0.x, w0, acc.x); acc.y = fmaf((float)h0.y, w0, acc.y);
        acc.z = fmaf((float)h0.z, w0, acc.z); acc.w = fmaf((float)h0.w, w0, acc.w);
    }
    acc.x += acc2.x; acc.y += acc2.y; acc.z += acc2.z; acc.w += acc2.w;

    h16x4 o;   // fused relu + fp16 store (feeds FC)
    o.x = (h16)fmaxf(acc.x, 0.f); o.y = (h16)fmaxf(acc.y, 0.f);
    o.z = (h16)fmaxf(acc.z, 0.f); o.w = (h16)fmaxf(acc.w, 0.f);
    *reinterpret_cast<h16x4*>(P + (size_t)node * 256 + j) = o;
}

// ---------------- fp16 2-product MFMA GEMM ----------------
// C[M,256] ~= A @ (Wh + Wl)^T * (1/64) ; A [M,K] fp16, Wh/Wl [256,K] fp16 (x64 scaled).
// SPLIT: epilogue +bias, relu -> fp16 Out.  else: fp16 Out (no bias/relu).
template<bool SPLIT>
__global__ __launch_bounds__(256) void k_gemm_f16(const h16* __restrict__ Ag,
                                                  const h16* __restrict__ Bhg,
                                                  const h16* __restrict__ Blg,
                                                  h16* __restrict__ Out,
                                                  const float* __restrict__ bias,
                                                  int M, int K) {
    __shared__ __attribute__((aligned(16))) char ldsA[8192];
    __shared__ __attribute__((aligned(16))) char ldsBh[8192];
    __shared__ __attribute__((aligned(16))) char ldsBl[8192];
    const int tid = threadIdx.x;
    const int lane = tid & 63, wid = tid >> 6;
    const int quad = lane >> 4, l16 = lane & 15;
    const int rowBase = blockIdx.x * 128;
    const int colBase = blockIdx.y * 128;
    const int wm = (wid & 1) * 64, wn = (wid >> 1) * 64;

    floatx4 acc[4][4] = {};

    // chunk c (16B = 8 fp16): row = (c>>6)*16 + (c&15), k-quad = (c>>4)&3
    const int c0 = wid * 64 + lane;
    const int c1 = c0 + 256;
    const int r0 = ((c0 >> 6) << 4) + (c0 & 15), q0 = (c0 >> 4) & 3;
    const int r1 = ((c1 >> 6) << 4) + (c1 & 15), q1 = (c1 >> 4) & 3;
    const size_t aoff0 = (size_t)(rowBase + r0) * K + q0 * 8;
    const size_t aoff1 = (size_t)(rowBase + r1) * K + q1 * 8;
    const size_t boff0 = (size_t)(colBase + r0) * K + q0 * 8;
    const size_t boff1 = (size_t)(colBase + r1) * K + q1 * 8;
    const int lo0 = (wid * 64) * 16;
    const int lo1 = (256 + wid * 64) * 16;

    for (int k0 = 0; k0 < K; k0 += 32) {
        load_lds16(ldsA + lo0, Ag + aoff0 + k0);
        load_lds16(ldsA + lo1, Ag + aoff1 + k0);
        load_lds16(ldsBh + lo0, Bhg + boff0 + k0);
        load_lds16(ldsBh + lo1, Bhg + boff1 + k0);
        load_lds16(ldsBl + lo0, Blg + boff0 + k0);
        load_lds16(ldsBl + lo1, Blg + boff1 + k0);
        __syncthreads();

        const half8* vA  = (const half8*)ldsA;
        const half8* vBh = (const half8*)ldsBh;
        const half8* vBl = (const half8*)ldsBl;
        half8 af[4], bfh[4], bfl[4];
#pragma unroll
        for (int mi = 0; mi < 4; ++mi)
            af[mi] = vA[((wm >> 4) + mi) * 64 + quad * 16 + l16];
#pragma unroll
        for (int ni = 0; ni < 4; ++ni) {
            int idx = ((wn >> 4) + ni) * 64 + quad * 16 + l16;
            bfh[ni] = vBh[idx];
            bfl[ni] = vBl[idx];
        }
#pragma unroll
        for (int mi = 0; mi < 4; ++mi)
#pragma unroll
            for (int ni = 0; ni < 4; ++ni) {
                acc[mi][ni] = __builtin_amdgcn_mfma_f32_16x16x32_f16(af[mi], bfh[ni], acc[mi][ni], 0, 0, 0);
                acc[mi][ni] = __builtin_amdgcn_mfma_f32_16x16x32_f16(af[mi], bfl[ni], acc[mi][ni], 0, 0, 0);
            }
        __syncthreads();
    }

    // C/D layout: col=l16, row=quad*4+reg
#pragma unroll
    for (int mi = 0; mi < 4; ++mi) {
#pragma unroll
        for (int r = 0; r < 4; ++r) {
            int grow = rowBase + wm + mi * 16 + quad * 4 + r;
            if (grow < M) {
#pragma unroll
                for (int ni = 0; ni < 4; ++ni) {
                    int gcol = colBase + wn + ni * 16 + l16;
                    float v = acc[mi][ni][r] * WINV;
                    if (SPLIT) v = fmaxf(v + bias[gcol], 0.f);
                    Out[(size_t)grow * 256 + gcol] = (h16)v;
                }
            }
        }
    }
}

// ---------------- FC: out[M,40] = X16[M,256] @ W[256,40] + b  (X16 already relu'd fp16) ----------------
__global__ __launch_bounds__(256) void k_fc(float* __restrict__ out, const h16* __restrict__ X,
                                            const float* __restrict__ W, const float* __restrict__ bias,
                                            int M) {
    __shared__ float Ws[256 * 40];
    __shared__ float Xs[32][69];
    const int tid = threadIdx.x;
#pragma unroll
    for (int t = 0; t < 10; ++t) {
        int idx = (t * 256 + tid) * 4;
        *reinterpret_cast<float4*>(&Ws[idx]) = *reinterpret_cast<const float4*>(W + idx);
    }
    const int rowBase = blockIdx.x * 64;
    const int r  = tid >> 2;
    const int cg = (tid & 3) * 10;
    const int kq = (tid & 3) << 3;
    float acc[10] = {};

    for (int k0 = 0; k0 < 256; k0 += 32) {
        int rr = rowBase + r;
        h16x8 v = {};
        if (rr < M) v = *reinterpret_cast<const h16x8*>(X + (size_t)rr * 256 + k0 + kq);
#pragma unroll
        for (int j = 0; j < 8; ++j) Xs[kq + j][r] = (float)v[j];
        __syncthreads();
#pragma unroll
        for (int kk = 0; kk < 32; ++kk) {
            float xv = Xs[kk][r];
#pragma unroll
            for (int j = 0; j < 10; ++j)
                acc[j] = fmaf(xv, Ws[(k0 + kk) * 40 + cg + j], acc[j]);
        }
        __syncthreads();
    }

    int orow = rowBase + r;
    if (orow < M) {
#pragma unroll
        for (int j = 0; j < 10; ++j)
            out[(size_t)orow * 40 + cg + j] = acc[j] + bias[cg + j];
    }
}

extern "C" void kernel_launch(void* const* d_in, const int* in_sizes, int n_in,
                              void* d_out, int out_size, void* d_ws, size_t ws_size,
                              hipStream_t stream) {
    const float* x   = (const float*)d_in[0];
    const int*   ei  = (const int*)d_in[1];
    const float* ea  = (const float*)d_in[2];
    const float* W1  = (const float*)d_in[3];
    const float* b1  = (const float*)d_in[4];
    const float* W2  = (const float*)d_in[5];
    const float* b2  = (const float*)d_in[6];
    const float* fcW = (const float*)d_in[7];
    const float* fcb = (const float*)d_in[8];
    float* out = (float*)d_out;

    const int n = NODES, e = EDGES;
    const int* row = ei;
    const int* col = ei + e;

    char* ws = (char*)d_ws;
    char*  Areg   = ws;                                        // 102,400,000 B
    char*  Breg   = ws + 102400000u;                           // 102,400,000 B
    float* dinv   = (float*)(ws + 204800000u);                 // 400,000 B
    unsigned long long* packed = (unsigned long long*)(ws + 205200000u); // 800,000 B
    int*   rowptr = (int*)  (ws + 206000000u);                 // 400,016 B
    int2*  meta   = (int2*) (ws + 206400016u);                 // 12,800,000 B -> 219,200,016
    h16*   W1h    = (h16*)  (ws + 219200016u);                 // 65,536 B
    h16*   W1l    = (h16*)  (ws + 219265552u);                 // 65,536 B
    h16*   W2h    = (h16*)  (ws + 219331088u);                 // 131,072 B
    h16*   W2l    = (h16*)  (ws + 219462160u);                 // 131,072 B -> 219,593,232

    // overlays (time-shared):
    int* partials = (int*)Areg;                                // scan temp (dies after scan3)
    h16* Xa16 = (h16*)Areg;                                    // 25.6 MB agg(x) fp16 [phase 1, after scan3]
    h16* x16  = (h16*)(Areg + 25600000u);                      // 25.6 MB fp16 x      [phase 1]
    h16* H2h  = (h16*)Areg;                                    // 51.2 MB GEMM2 out   [phase 2]
    unsigned short* rank = (unsigned short*)Breg;              // 3.2 MB (dies after build)
    h16* P1   = (h16*)Breg;                                    // 51.2 MB relu(P1) fp16 [after build]
    h16* P2h  = (h16*)(Breg + 51200000u);                      // 51.2 MB gather2 out  [phase 3]

    const int nb = (n + 255) / 256;   // 391
    const int eb = e / 256;           // 6250

    // ---- CSR build + (fused) weight/input conversion ----
    k_init<<<nb, 256, 0, stream>>>(packed, n);
    k_hist<<<19134, 256, 0, stream>>>(packed, rank, col, ea, e,
                                      W1, W1h, W1l, W2, W2h, W2l, x, x16, n);
    k_scan1<<<nb, 256, 0, stream>>>(packed, rowptr, partials, dinv, n);
    k_scan2<<<1, 512, 0, stream>>>(partials, nb);
    k_scan3<<<nb, 256, 0, stream>>>(rowptr, partials, n);
    k_build<<<eb, 256, 0, stream>>>(rowptr, rank, meta, row, col, ea, dinv, e);

    dim3 gg((n + 127) / 128, 2);

    // layer 1 (agg-first): Xagg = agg(x16) fp16 ; P1 = relu(Xagg@W1 + b1) fp16
    k_gather_x<<<(n + 3) / 4, 256, 0, stream>>>(Xa16, x16, dinv, rowptr, meta, n);
    k_gemm_f16<true><<<gg, 256, 0, stream>>>(Xa16, W1h, W1l, P1, b1, n, 128);

    // layer 2: H2 = P1 @ W2 fp16 ; P2 = relu(agg(H2) + b2) fp16
    k_gemm_f16<false><<<gg, 256, 0, stream>>>(P1, W2h, W2l, H2h, nullptr, n, 256);
    k_gather<<<(n + 3) / 4, 256, 0, stream>>>(P2h, H2h, dinv, rowptr, meta, b2, n);

    // classifier
    k_fc<<<(n + 63) / 64, 256, 0, stream>>>(out, P2h, fcW, fcb, n);
}